// Round 11
// baseline (1143.194 us; speedup 1.0000x reference)
//
#include <hip/hip_runtime.h>

#define NN 50000
#define NE 800000

typedef _Float16 f16;
typedef _Float16 f16x8 __attribute__((ext_vector_type(8)));
typedef float f32x4 __attribute__((ext_vector_type(4)));

__device__ __forceinline__ f16x8 fzero8() {
  f16x8 v;
#pragma unroll
  for (int i = 0; i < 8; ++i) v[i] = (f16)0.f;
  return v;
}

__device__ __forceinline__ f32x4 mfma16(f16x8 a, f16x8 b, f32x4 c) {
  return __builtin_amdgcn_mfma_f32_16x16x32_f16(a, b, c, 0, 0, 0);
}

// ---------------- prep kernels ----------------

__global__ void count_kernel(const int* __restrict__ dst, int* __restrict__ cnt) {
  int e = blockIdx.x * 256 + threadIdx.x;
  if (e < NE) atomicAdd(&cnt[dst[e]], 1);
}

// single-block exclusive scan over cnt -> off/cur, plus inv = 1/max(cnt,1)
__global__ void scan_kernel(const int* __restrict__ cnt, int* __restrict__ off,
                            int* __restrict__ cur, float* __restrict__ inv) {
  __shared__ int part[1024];
  const int t = threadIdx.x;
  const int CH = (NN + 1023) / 1024;
  const int i0 = t * CH, i1 = (i0 + CH < NN) ? i0 + CH : NN;
  int s = 0;
  for (int i = i0; i < i1; ++i) s += cnt[i];
  part[t] = s;
  __syncthreads();
  for (int d = 1; d < 1024; d <<= 1) {
    int v = (t >= d) ? part[t - d] : 0;
    __syncthreads();
    part[t] += v;
    __syncthreads();
  }
  int base = (t > 0) ? part[t - 1] : 0;
  for (int i = i0; i < i1; ++i) {
    off[i] = base;
    cur[i] = base;
    inv[i] = 1.0f / fmaxf((float)cnt[i], 1.0f);
    base += cnt[i];
  }
  if (t == 1023) off[NN] = NE;
}

// scatter edges into dst-sorted order; also build packed encoder rows
__global__ void scatter_pack(const float* __restrict__ x, const float* __restrict__ ea,
                             const int* __restrict__ src, const int* __restrict__ dst,
                             int* __restrict__ cur, int* __restrict__ psrc,
                             int* __restrict__ pdst, f16* __restrict__ A) {
  int e = blockIdx.x * 256 + threadIdx.x;
  if (e >= NE) return;
  int s = src[e], d = dst[e];
  int pos = atomicAdd(&cur[d], 1);
  psrc[pos] = s;
  pdst[pos] = d;
  f16 row[16];
#pragma unroll
  for (int i = 0; i < 5; ++i) { row[i] = (f16)x[s * 5 + i]; row[5 + i] = (f16)x[d * 5 + i]; }
#pragma unroll
  for (int i = 0; i < 4; ++i) row[10 + i] = (f16)ea[e * 4 + i];
  row[14] = (f16)0.f; row[15] = (f16)0.f;
  *(f16x8*)(A + (size_t)pos * 16) = *(f16x8*)row;
  *(f16x8*)(A + (size_t)pos * 16 + 8) = *(f16x8*)(row + 8);
}

// all 13 weight transposes in one launch; block b handles matrix b
struct PrepPtrs { const float* W[13]; };
__global__ void prep_all(PrepPtrs P, f16* __restrict__ out) {
  const int Nw[13]   = {64,64,64,64,64,64,64,64,64,64,64,64,7};
  const int Kd[13]   = {32,64,96,96,64,192,64,128,64,192,64,128,64};
  const int ks[13]   = {0,0,0,5,0,0,0,0,0,0,0,0,0};
  const int kd[13]   = {0,0,0,32,0,0,0,0,0,0,0,0,0};
  const int klen[13] = {14,64,5,64,64,192,64,128,64,192,64,128,64};
  const int nc[13]   = {64,64,64,64,64,64,64,64,64,64,64,64,7};
  const int ofs[13]  = {0,2048,6144,6144,12288,16384,28672,32768,40960,45056,57344,61440,69632};
  const int m = blockIdx.x;
  const float* W = P.W[m];
  const int tot = klen[m] * nc[m];
  for (int idx = threadIdx.x; idx < tot; idx += 256) {
    int kk = idx / nc[m], n = idx % nc[m];
    out[ofs[m] + n * Kd[m] + kd[m] + kk] = (f16)W[(ks[m] + kk) * Nw[m] + n];
  }
}

// ---------------- edge MLP (LDS B1, register B2, 1-deep A pipeline, 4 blk/CU) ----------------
// STAGE: 0=encoder (A from packed Aenc, write el, agg += el)
//        1=processor (A=[xh[src]|xh[dst]|el], el += ed in place, agg += ed)
//        2=decoder   (A same as proc, NO el write, agg += ed)
template <int STAGE, int KT1>
__global__
__attribute__((amdgpu_flat_work_group_size(256, 256), amdgpu_waves_per_eu(4, 4)))
void edge_mlp_kernel(const f16* __restrict__ Aenc,
                     const f16* __restrict__ xh,
                     const f16* elr, f16* elw,
                     const int* __restrict__ psrc,
                     const int* __restrict__ pdst,
                     const f16* __restrict__ B1,
                     const f16* __restrict__ B2,
                     const float* __restrict__ b1,
                     const float* __restrict__ b2,
                     float* __restrict__ agg) {
  constexpr int K1 = KT1 * 32;
  constexpr int NF1 = KT1 * 4;              // L1 fragment count
  constexpr int NA = (STAGE == 0) ? 1 : 6;  // A fragments per group
  __shared__ __align__(16) f16 h1s[4][16][72];    // 9216 B
  __shared__ __align__(16) f16 B1s[NF1 * 64 * 8]; // KT1=6: 24576 B -> total 33792, 4 blk/CU

  const int wave = threadIdx.x >> 6;
  const int lane = threadIdx.x & 63;
  const int l15 = lane & 15, lg = lane >> 4;
  const int nwaves = gridDim.x * 4;
  const int wid = blockIdx.x * 4 + wave;
  const int NG = NE / 16;

  // ---- stage L1 weight fragments into LDS (fragment-major, conflict-free) ----
  for (int f = wave; f < NF1; f += 4) {
    const int kk = f >> 2, nt = f & 3;
    *(f16x8*)&B1s[(f * 64 + lane) * 8] =
        *(const f16x8*)(B1 + (nt * 16 + l15) * K1 + kk * 32 + lg * 8);
  }
  // ---- L2 weights in registers (8 frags = 32 VGPR; L3-resident read, once) ----
  f16x8 B2f[2][4];
#pragma unroll
  for (int kk = 0; kk < 2; ++kk)
#pragma unroll
    for (int nt = 0; nt < 4; ++nt)
      B2f[kk][nt] = *(const f16x8*)(B2 + (nt * 16 + l15) * 64 + kk * 32 + lg * 8);
  float bias1[4], bias2[4];
#pragma unroll
  for (int nt = 0; nt < 4; ++nt) { bias1[nt] = b1[nt * 16 + l15]; bias2[nt] = b2[nt * 16 + l15]; }
  __syncthreads();

  // ---- A-fragment loader ----
  auto loadA = [&](int g, int s, int d, f16x8* a) {
    const int erA = g * 16 + l15;
    if (STAGE == 0) {
      a[0] = fzero8();
      if (lg < 2) a[0] = *(const f16x8*)(Aenc + (size_t)erA * 16 + lg * 8);
    } else {
      a[0] = *(const f16x8*)(xh + (size_t)s * 64 + lg * 8);
      a[1] = *(const f16x8*)(xh + (size_t)s * 64 + 32 + lg * 8);
      a[2] = *(const f16x8*)(xh + (size_t)d * 64 + lg * 8);
      a[3] = *(const f16x8*)(xh + (size_t)d * 64 + 32 + lg * 8);
      a[4] = *(const f16x8*)(elr + (size_t)erA * 64 + lg * 8);
      a[5] = *(const f16x8*)(elr + (size_t)erA * 64 + 32 + lg * 8);
    }
  };

  // ---- software pipeline: idx 2-deep, A-frags 1-deep (R7-proven) ----
  int sA = 0, dA = 0, sB = 0, dB = 0;
  dA = pdst[wid * 16 + l15];
  if (STAGE != 0) sA = psrc[wid * 16 + l15];
  f16x8 aCur[NA], aNxt[NA];
  loadA(wid, sA, dA, aCur);
  {
    const int g2 = wid + nwaves;
    if (g2 < NG) {
      dB = pdst[g2 * 16 + l15];
      if (STAGE != 0) sB = psrc[g2 * 16 + l15];
    }
  }

  for (int g = wid; g < NG; g += nwaves) {
    const int gN = g + nwaves;
    if (gN < NG) loadA(gN, sB, dB, aNxt);          // prefetch next group's A
    int sC = 0, dC = 0;
    const int g3 = g + 2 * nwaves;
    if (g3 < NG) {                                  // prefetch idx 2 ahead
      dC = pdst[g3 * 16 + l15];
      if (STAGE != 0) sC = psrc[g3 * 16 + l15];
    }

    // ---- layer 1: MFMA with LDS B-frags ----
    f32x4 acc[4];
#pragma unroll
    for (int nt = 0; nt < 4; ++nt) { acc[nt][0] = 0.f; acc[nt][1] = 0.f; acc[nt][2] = 0.f; acc[nt][3] = 0.f; }
#pragma unroll
    for (int kk = 0; kk < KT1; ++kk) {
      const f16x8 a = aCur[(STAGE == 0) ? 0 : kk];
#pragma unroll
      for (int nt = 0; nt < 4; ++nt) {
        const f16x8 b = *(const f16x8*)&B1s[((kk * 4 + nt) * 64 + lane) * 8];
        acc[nt] = mfma16(a, b, acc[nt]);
      }
    }
    // bias + relu, stage h1 to LDS (C-layout -> A-layout); per-wave slice
#pragma unroll
    for (int nt = 0; nt < 4; ++nt)
#pragma unroll
      for (int r = 0; r < 4; ++r) {
        float h = fmaxf(acc[nt][r] + bias1[nt], 0.f);
        h1s[wave][lg * 4 + r][nt * 16 + l15] = (f16)h;
      }

    // ---- layer 2 (register B-frags) ----
    f32x4 out[4];
#pragma unroll
    for (int nt = 0; nt < 4; ++nt) { out[nt][0] = 0.f; out[nt][1] = 0.f; out[nt][2] = 0.f; out[nt][3] = 0.f; }
#pragma unroll
    for (int kk = 0; kk < 2; ++kk) {
      const f16x8 hf = *(const f16x8*)&h1s[wave][l15][kk * 32 + lg * 8];
#pragma unroll
      for (int nt = 0; nt < 4; ++nt) out[nt] = mfma16(hf, B2f[kk][nt], out[nt]);
    }

    // stage ed (bias added) back to LDS rows
#pragma unroll
    for (int nt = 0; nt < 4; ++nt)
#pragma unroll
      for (int r = 0; r < 4; ++r)
        h1s[wave][lg * 4 + r][nt * 16 + l15] = (f16)(out[nt][r] + bias2[nt]);

    // global el write (encoder: fresh; proc: in-place residual; decoder: none)
    const int erA = g * 16 + l15;
    if (STAGE != 2) {
      f16x8 v0 = *(const f16x8*)&h1s[wave][l15][lg * 8];
      f16x8 v1 = *(const f16x8*)&h1s[wave][l15][32 + lg * 8];
      f16* p0 = elw + (size_t)erA * 64 + lg * 8;
      if (STAGE == 1) {
        f16x8 n0, n1;
#pragma unroll
        for (int j = 0; j < 8; ++j) {
          n0[j] = (f16)((float)aCur[4][j] + (float)v0[j]);
          n1[j] = (f16)((float)aCur[5][j] + (float)v1[j]);
        }
        *(f16x8*)p0 = n0;
        *(f16x8*)(p0 + 32) = n1;
      } else {
        *(f16x8*)p0 = v0;
        *(f16x8*)(p0 + 32) = v1;
      }
    }

    // fused segmented reduction: lane = column, walk 16 sorted rows,
    // one coalesced 64-lane atomicAdd per dst segment (dst wave-uniform).
    {
      float racc = 0.f;
      int dprev = __shfl(dA, 0);
#pragma unroll
      for (int row = 0; row < 16; ++row) {
        const int dn = __shfl(dA, row);
        const float v = (float)h1s[wave][row][lane];
        if (dn != dprev) {
          atomicAdd(agg + (size_t)dprev * 64 + lane, racc);
          racc = 0.f;
          dprev = dn;
        }
        racc += v;
      }
      atomicAdd(agg + (size_t)dprev * 64 + lane, racc);
    }

    // rotate pipeline
#pragma unroll
    for (int i = 0; i < NA; ++i) aCur[i] = aNxt[i];
    sA = sB; dA = dB; sB = sC; dB = dC;
  }
}

// ---------------- node MLP (LDS-staged weights, fused mean-finish) ----------------
// STAGE: 0=encoder (A=[x_raw(5,pad32)|agg*inv], out: xl=v, xh=f16(v))
//        1=processor (A=[xh|agg*inv], xl += v, xh mirror)
//        2=decoder   (A=[xh|agg*inv], write d_out[N][7])
template <int STAGE, int KT1, int NT2, int OUTW>
__global__ __launch_bounds__(256, 4)
void node_mlp_kernel(const float* __restrict__ xraw,
                     const f16* xh,
                     const float* __restrict__ agg,
                     const float* __restrict__ inv,
                     const f16* __restrict__ B1,
                     const f16* __restrict__ B2,
                     const float* __restrict__ b1,
                     const float* __restrict__ b2,
                     float* __restrict__ xl,
                     f16* xho,
                     float* __restrict__ outp) {
  constexpr int K1 = KT1 * 32;
  constexpr int NF1 = KT1 * 4;
  constexpr int NF2 = 2 * NT2;
  __shared__ __align__(16) f16 h1s[4][16][72];
  __shared__ __align__(16) f16 B1s[NF1 * 64 * 8];
  __shared__ __align__(16) f16 B2s[NF2 * 64 * 8];
  const int wave = threadIdx.x >> 6;
  const int lane = threadIdx.x & 63;
  const int l15 = lane & 15, lg = lane >> 4;
  const int nwaves = gridDim.x * 4;
  const int wid = blockIdx.x * 4 + wave;
  const int NG = NN / 16;

  for (int f = wave; f < NF1; f += 4) {
    const int kk = f >> 2, nt = f & 3;
    *(f16x8*)&B1s[(f * 64 + lane) * 8] =
        *(const f16x8*)(B1 + (nt * 16 + l15) * K1 + kk * 32 + lg * 8);
  }
  for (int f = wave; f < NF2; f += 4) {
    const int kk = f / NT2, nt = f % NT2;
    *(f16x8*)&B2s[(f * 64 + lane) * 8] =
        *(const f16x8*)(B2 + (nt * 16 + l15) * 64 + kk * 32 + lg * 8);
  }
  float bias1[4], bias2[NT2];
#pragma unroll
  for (int nt = 0; nt < 4; ++nt) bias1[nt] = b1[nt * 16 + l15];
#pragma unroll
  for (int nt = 0; nt < NT2; ++nt) bias2[nt] = (nt * 16 + l15 < OUTW) ? b2[nt * 16 + l15] : 0.f;
  __syncthreads();

  for (int g = wid; g < NG; g += nwaves) {
    const int n0 = g * 16;
    const int rA = n0 + l15;
    const float iv = inv[rA];

    f32x4 acc[4];
#pragma unroll
    for (int nt = 0; nt < 4; ++nt) { acc[nt][0] = 0.f; acc[nt][1] = 0.f; acc[nt][2] = 0.f; acc[nt][3] = 0.f; }

#pragma unroll
    for (int kk = 0; kk < KT1; ++kk) {
      f16x8 a;
      if (STAGE == 0 && kk == 0) {
        a = fzero8();
        if (lg == 0) {
#pragma unroll
          for (int j = 0; j < 5; ++j) a[j] = (f16)xraw[(size_t)rA * 5 + j];
        }
      } else if (STAGE != 0 && kk < 2) {
        a = *(const f16x8*)(xh + (size_t)rA * 64 + kk * 32 + lg * 8);
      } else {
        const int ko = (STAGE == 0) ? (kk - 1) : (kk - 2);
        const float* ap = agg + (size_t)rA * 64 + ko * 32 + lg * 8;
        f32x4 a0 = *(const f32x4*)ap;
        f32x4 a1 = *(const f32x4*)(ap + 4);
#pragma unroll
        for (int j = 0; j < 4; ++j) { a[j] = (f16)(a0[j] * iv); a[4 + j] = (f16)(a1[j] * iv); }
      }
#pragma unroll
      for (int nt = 0; nt < 4; ++nt) {
        const f16x8 b = *(const f16x8*)&B1s[((kk * 4 + nt) * 64 + lane) * 8];
        acc[nt] = mfma16(a, b, acc[nt]);
      }
    }
#pragma unroll
    for (int nt = 0; nt < 4; ++nt)
#pragma unroll
      for (int r = 0; r < 4; ++r) {
        float h = fmaxf(acc[nt][r] + bias1[nt], 0.f);
        h1s[wave][lg * 4 + r][nt * 16 + l15] = (f16)h;
      }

    f32x4 out[NT2];
#pragma unroll
    for (int nt = 0; nt < NT2; ++nt) { out[nt][0] = 0.f; out[nt][1] = 0.f; out[nt][2] = 0.f; out[nt][3] = 0.f; }
#pragma unroll
    for (int kk = 0; kk < 2; ++kk) {
      const f16x8 hf = *(const f16x8*)&h1s[wave][l15][kk * 32 + lg * 8];
#pragma unroll
      for (int nt = 0; nt < NT2; ++nt) {
        const f16x8 b = *(const f16x8*)&B2s[((kk * NT2 + nt) * 64 + lane) * 8];
        out[nt] = mfma16(hf, b, out[nt]);
      }
    }
#pragma unroll
    for (int r = 0; r < 4; ++r) {
      const int row = n0 + lg * 4 + r;
#pragma unroll
      for (int nt = 0; nt < NT2; ++nt) {
        const int col = nt * 16 + l15;
        float v = out[nt][r] + bias2[nt];
        if (STAGE == 0) {
          xl[(size_t)row * 64 + col] = v;
          xho[(size_t)row * 64 + col] = (f16)v;
        } else if (STAGE == 1) {
          float nv = xl[(size_t)row * 64 + col] + v;
          xl[(size_t)row * 64 + col] = nv;
          xho[(size_t)row * 64 + col] = (f16)nv;
        } else {
          if (col < OUTW) outp[(size_t)row * OUTW + col] = v;
        }
      }
    }
  }
}

// ---------------- launch ----------------

extern "C" void kernel_launch(void* const* d_in, const int* in_sizes, int n_in,
                              void* d_out, int out_size, void* d_ws, size_t ws_size,
                              hipStream_t stream) {
  const float* x  = (const float*)d_in[0];
  const int* ei   = (const int*)d_in[1];
  const float* ea = (const float*)d_in[2];
  const float* enc_e_b1 = (const float*)d_in[4];
  const float* enc_e_b2 = (const float*)d_in[6];
  const float* enc_n_b1 = (const float*)d_in[8];
  const float* enc_n_b2 = (const float*)d_in[10];
  const float* proc_e_b1 = (const float*)d_in[12];
  const float* proc_e_b2 = (const float*)d_in[14];
  const float* proc_n_b1 = (const float*)d_in[16];
  const float* proc_n_b2 = (const float*)d_in[18];
  const float* dec_e_b1 = (const float*)d_in[20];
  const float* dec_e_b2 = (const float*)d_in[22];
  const float* dec_n_b1 = (const float*)d_in[24];
  const float* dec_n_b2 = (const float*)d_in[26];

  const int* src = ei;
  const int* dst = ei + NE;

  // workspace layout (~167 MB total; R2 proved >= 263 MB available)
  char* p = (char*)d_ws;
  f16* el    = (f16*)p;   p += (size_t)NE * 64 * 2;   // 102.4 MB
  f16* Aenc  = (f16*)p;   p += (size_t)NE * 16 * 2;   // 25.6 MB
  float* xl  = (float*)p; p += (size_t)NN * 64 * 4;   // 12.8 MB
  f16* xh    = (f16*)p;   p += (size_t)NN * 64 * 2;   // 6.4 MB
  float* agg = (float*)p; p += (size_t)NN * 64 * 4;   // 12.8 MB f32 atomic accumulator
  int* cnt   = (int*)p;   p += (size_t)NN * 4;
  int* off   = (int*)p;   p += (size_t)(NN + 1) * 4;
  int* cur   = (int*)p;   p += (size_t)NN * 4;
  float* inv = (float*)p; p += (size_t)NN * 4;
  int* psrc  = (int*)p;   p += (size_t)NE * 4;
  int* pdst  = (int*)p;   p += (size_t)NE * 4;
  f16* wb    = (f16*)p;   p += 70656 * 2;
  f16* W1T_ence = wb + 0;
  f16* W2T_ence = wb + 2048;
  f16* W1T_encn = wb + 6144;
  f16* W2T_encn = wb + 12288;
  f16* W1T_proce = wb + 16384;
  f16* W2T_proce = wb + 28672;
  f16* W1T_procn = wb + 32768;
  f16* W2T_procn = wb + 40960;
  f16* W1T_dece = wb + 45056;
  f16* W2T_dece = wb + 57344;
  f16* W1T_decn = wb + 61440;
  f16* W2T_decn = wb + 69632;

  hipMemsetAsync(cnt, 0, (size_t)NN * 4, stream);
  hipMemsetAsync(wb, 0, 70656 * 2, stream);

  count_kernel<<<(NE + 255) / 256, 256, 0, stream>>>(dst, cnt);
  scan_kernel<<<1, 1024, 0, stream>>>(cnt, off, cur, inv);
  scatter_pack<<<(NE + 255) / 256, 256, 0, stream>>>(x, ea, src, dst, cur, psrc, pdst, Aenc);

  PrepPtrs P;
  P.W[0]  = (const float*)d_in[3];   // enc_e_w1
  P.W[1]  = (const float*)d_in[5];   // enc_e_w2
  P.W[2]  = (const float*)d_in[7];   // enc_n_w1 (raw part)
  P.W[3]  = (const float*)d_in[7];   // enc_n_w1 (agg part)
  P.W[4]  = (const float*)d_in[9];   // enc_n_w2
  P.W[5]  = (const float*)d_in[11];  // proc_e_w1
  P.W[6]  = (const float*)d_in[13];  // proc_e_w2
  P.W[7]  = (const float*)d_in[15];  // proc_n_w1
  P.W[8]  = (const float*)d_in[17];  // proc_n_w2
  P.W[9]  = (const float*)d_in[19];  // dec_e_w1
  P.W[10] = (const float*)d_in[21];  // dec_e_w2
  P.W[11] = (const float*)d_in[23];  // dec_n_w1
  P.W[12] = (const float*)d_in[25];  // dec_n_w2
  prep_all<<<13, 256, 0, stream>>>(P, wb);

  const int EDGE_BLK = 2048;  // strided mapping, 8192 waves
  const size_t AGG_BYTES = (size_t)NN * 64 * 4;

  // ---- encoder ----
  hipMemsetAsync(agg, 0, AGG_BYTES, stream);
  edge_mlp_kernel<0, 1><<<EDGE_BLK, 256, 0, stream>>>(Aenc, xh, el, el, psrc, pdst,
                                                      W1T_ence, W2T_ence, enc_e_b1, enc_e_b2, agg);
  node_mlp_kernel<0, 3, 4, 64><<<256, 256, 0, stream>>>(x, xh, agg, inv, W1T_encn, W2T_encn,
                                                        enc_n_b1, enc_n_b2, xl, xh, (float*)d_out);
  // ---- 2 processor rounds (shared weights, residuals) ----
  for (int r = 0; r < 2; ++r) {
    hipMemsetAsync(agg, 0, AGG_BYTES, stream);
    edge_mlp_kernel<1, 6><<<EDGE_BLK, 256, 0, stream>>>(Aenc, xh, el, el, psrc, pdst,
                                                        W1T_proce, W2T_proce, proc_e_b1, proc_e_b2, agg);
    node_mlp_kernel<1, 4, 4, 64><<<256, 256, 0, stream>>>(x, xh, agg, inv, W1T_procn, W2T_procn,
                                                          proc_n_b1, proc_n_b2, xl, xh, (float*)d_out);
  }
  // ---- decoder (no el write; agg of ed only) ----
  hipMemsetAsync(agg, 0, AGG_BYTES, stream);
  edge_mlp_kernel<2, 6><<<EDGE_BLK, 256, 0, stream>>>(Aenc, xh, el, el, psrc, pdst,
                                                      W1T_dece, W2T_dece, dec_e_b1, dec_e_b2, agg);
  node_mlp_kernel<2, 4, 1, 7><<<256, 256, 0, stream>>>(x, xh, agg, inv, W1T_decn, W2T_decn,
                                                       dec_n_b1, dec_n_b2, xl, xh, (float*)d_out);
}

// Round 12
// 767.017 us; speedup vs baseline: 1.4904x; 1.4904x over previous
//
#include <hip/hip_runtime.h>

#define NN 50000
#define NE 800000

typedef _Float16 f16;
typedef _Float16 f16x8 __attribute__((ext_vector_type(8)));
typedef float f32x4 __attribute__((ext_vector_type(4)));

__device__ __forceinline__ f16x8 fzero8() {
  f16x8 v;
#pragma unroll
  for (int i = 0; i < 8; ++i) v[i] = (f16)0.f;
  return v;
}

__device__ __forceinline__ f32x4 mfma16(f16x8 a, f16x8 b, f32x4 c) {
  return __builtin_amdgcn_mfma_f32_16x16x32_f16(a, b, c, 0, 0, 0);
}

// ---------------- prep kernels ----------------

__global__ void count_kernel(const int* __restrict__ dst, int* __restrict__ cnt) {
  int e = blockIdx.x * 256 + threadIdx.x;
  if (e < NE) atomicAdd(&cnt[dst[e]], 1);
}

// single-block exclusive scan over cnt -> off/cur, plus inv = 1/max(cnt,1)
__global__ void scan_kernel(const int* __restrict__ cnt, int* __restrict__ off,
                            int* __restrict__ cur, float* __restrict__ inv) {
  __shared__ int part[1024];
  const int t = threadIdx.x;
  const int CH = (NN + 1023) / 1024;
  const int i0 = t * CH, i1 = (i0 + CH < NN) ? i0 + CH : NN;
  int s = 0;
  for (int i = i0; i < i1; ++i) s += cnt[i];
  part[t] = s;
  __syncthreads();
  for (int d = 1; d < 1024; d <<= 1) {
    int v = (t >= d) ? part[t - d] : 0;
    __syncthreads();
    part[t] += v;
    __syncthreads();
  }
  int base = (t > 0) ? part[t - 1] : 0;
  for (int i = i0; i < i1; ++i) {
    off[i] = base;
    cur[i] = base;
    inv[i] = 1.0f / fmaxf((float)cnt[i], 1.0f);
    base += cnt[i];
  }
  if (t == 1023) off[NN] = NE;
}

// scatter edges into dst-sorted order; also build packed encoder rows
__global__ void scatter_pack(const float* __restrict__ x, const float* __restrict__ ea,
                             const int* __restrict__ src, const int* __restrict__ dst,
                             int* __restrict__ cur, int* __restrict__ psrc,
                             int* __restrict__ pdst, f16* __restrict__ A) {
  int e = blockIdx.x * 256 + threadIdx.x;
  if (e >= NE) return;
  int s = src[e], d = dst[e];
  int pos = atomicAdd(&cur[d], 1);
  psrc[pos] = s;
  pdst[pos] = d;
  f16 row[16];
#pragma unroll
  for (int i = 0; i < 5; ++i) { row[i] = (f16)x[s * 5 + i]; row[5 + i] = (f16)x[d * 5 + i]; }
#pragma unroll
  for (int i = 0; i < 4; ++i) row[10 + i] = (f16)ea[e * 4 + i];
  row[14] = (f16)0.f; row[15] = (f16)0.f;
  *(f16x8*)(A + (size_t)pos * 16) = *(f16x8*)row;
  *(f16x8*)(A + (size_t)pos * 16 + 8) = *(f16x8*)(row + 8);
}

// all 13 weight transposes in one launch; block b handles matrix b
struct PrepPtrs { const float* W[13]; };
__global__ void prep_all(PrepPtrs P, f16* __restrict__ out) {
  const int Nw[13]   = {64,64,64,64,64,64,64,64,64,64,64,64,7};
  const int Kd[13]   = {32,64,96,96,64,192,64,128,64,192,64,128,64};
  const int ks[13]   = {0,0,0,5,0,0,0,0,0,0,0,0,0};
  const int kd[13]   = {0,0,0,32,0,0,0,0,0,0,0,0,0};
  const int klen[13] = {14,64,5,64,64,192,64,128,64,192,64,128,64};
  const int nc[13]   = {64,64,64,64,64,64,64,64,64,64,64,64,7};
  const int ofs[13]  = {0,2048,6144,6144,12288,16384,28672,32768,40960,45056,57344,61440,69632};
  const int m = blockIdx.x;
  const float* W = P.W[m];
  const int tot = klen[m] * nc[m];
  for (int idx = threadIdx.x; idx < tot; idx += 256) {
    int kk = idx / nc[m], n = idx % nc[m];
    out[ofs[m] + n * Kd[m] + kd[m] + kk] = (f16)W[(ks[m] + kk) * Nw[m] + n];
  }
}

// ---------------- edge MLP (R7 per-wave structure, 512-thread blocks) ----------------
// 8 waves/block amortize the block-wide LDS weight stage ->
// LDS 51200 B/block, 3 blocks/CU = 24 waves/CU = 6 waves/EU (matches 84-VGPR alloc).
// STAGE: 0=encoder (A from packed Aenc, write el, agg += el)
//        1=processor (A=[xh[src]|xh[dst]|el], el += ed in place, agg += ed)
//        2=decoder   (A same as proc, NO el write, agg += ed)
template <int STAGE, int KT1>
__global__ __launch_bounds__(512, 3)
void edge_mlp_kernel(const f16* __restrict__ Aenc,
                     const f16* __restrict__ xh,
                     const f16* elr, f16* elw,
                     const int* __restrict__ psrc,
                     const int* __restrict__ pdst,
                     const f16* __restrict__ B1,
                     const f16* __restrict__ B2,
                     const float* __restrict__ b1,
                     const float* __restrict__ b2,
                     float* __restrict__ agg) {
  constexpr int K1 = KT1 * 32;
  constexpr int NF1 = KT1 * 4;              // L1 fragment count
  constexpr int NA = (STAGE == 0) ? 1 : 6;  // A fragments per group
  __shared__ __align__(16) f16 h1s[8][16][72];    // 18432 B (per-wave slices)
  __shared__ __align__(16) f16 B1s[NF1 * 64 * 8]; // KT1=6: 24576 B
  __shared__ __align__(16) f16 B2s[8 * 64 * 8];   // 8192 B   (total 51200 B)

  const int wave = threadIdx.x >> 6;        // 0..7
  const int lane = threadIdx.x & 63;
  const int l15 = lane & 15, lg = lane >> 4;
  const int nwaves = gridDim.x * 8;
  const int wid = blockIdx.x * 8 + wave;
  const int NG = NE / 16;

  // ---- stage weight fragments into LDS (fragment-major, conflict-free reads) ----
  for (int f = wave; f < NF1; f += 8) {
    const int kk = f >> 2, nt = f & 3;
    *(f16x8*)&B1s[(f * 64 + lane) * 8] =
        *(const f16x8*)(B1 + (nt * 16 + l15) * K1 + kk * 32 + lg * 8);
  }
  for (int f = wave; f < 8; f += 8) {
    const int kk = f >> 2, nt = f & 3;
    *(f16x8*)&B2s[(f * 64 + lane) * 8] =
        *(const f16x8*)(B2 + (nt * 16 + l15) * 64 + kk * 32 + lg * 8);
  }
  float bias1[4], bias2[4];
#pragma unroll
  for (int nt = 0; nt < 4; ++nt) { bias1[nt] = b1[nt * 16 + l15]; bias2[nt] = b2[nt * 16 + l15]; }
  __syncthreads();

  // ---- A-fragment loader ----
  auto loadA = [&](int g, int s, int d, f16x8* a) {
    const int erA = g * 16 + l15;
    if (STAGE == 0) {
      a[0] = fzero8();
      if (lg < 2) a[0] = *(const f16x8*)(Aenc + (size_t)erA * 16 + lg * 8);
    } else {
      a[0] = *(const f16x8*)(xh + (size_t)s * 64 + lg * 8);
      a[1] = *(const f16x8*)(xh + (size_t)s * 64 + 32 + lg * 8);
      a[2] = *(const f16x8*)(xh + (size_t)d * 64 + lg * 8);
      a[3] = *(const f16x8*)(xh + (size_t)d * 64 + 32 + lg * 8);
      a[4] = *(const f16x8*)(elr + (size_t)erA * 64 + lg * 8);
      a[5] = *(const f16x8*)(elr + (size_t)erA * 64 + 32 + lg * 8);
    }
  };

  // ---- software pipeline: idx 2-deep, A-frags 1-deep (R7-proven) ----
  int sA = 0, dA = 0, sB = 0, dB = 0;
  dA = pdst[wid * 16 + l15];
  if (STAGE != 0) sA = psrc[wid * 16 + l15];
  f16x8 aCur[NA], aNxt[NA];
  loadA(wid, sA, dA, aCur);
  {
    const int g2 = wid + nwaves;
    if (g2 < NG) {
      dB = pdst[g2 * 16 + l15];
      if (STAGE != 0) sB = psrc[g2 * 16 + l15];
    }
  }

  for (int g = wid; g < NG; g += nwaves) {
    const int gN = g + nwaves;
    if (gN < NG) loadA(gN, sB, dB, aNxt);          // prefetch next group's A
    int sC = 0, dC = 0;
    const int g3 = g + 2 * nwaves;
    if (g3 < NG) {                                  // prefetch idx 2 ahead
      dC = pdst[g3 * 16 + l15];
      if (STAGE != 0) sC = psrc[g3 * 16 + l15];
    }

    // ---- layer 1: MFMA with LDS B-frags ----
    f32x4 acc[4];
#pragma unroll
    for (int nt = 0; nt < 4; ++nt) { acc[nt][0] = 0.f; acc[nt][1] = 0.f; acc[nt][2] = 0.f; acc[nt][3] = 0.f; }
#pragma unroll
    for (int kk = 0; kk < KT1; ++kk) {
      const f16x8 a = aCur[(STAGE == 0) ? 0 : kk];
#pragma unroll
      for (int nt = 0; nt < 4; ++nt) {
        const f16x8 b = *(const f16x8*)&B1s[((kk * 4 + nt) * 64 + lane) * 8];
        acc[nt] = mfma16(a, b, acc[nt]);
      }
    }
    // bias + relu, stage h1 to LDS (C-layout -> A-layout); per-wave slice
#pragma unroll
    for (int nt = 0; nt < 4; ++nt)
#pragma unroll
      for (int r = 0; r < 4; ++r) {
        float h = fmaxf(acc[nt][r] + bias1[nt], 0.f);
        h1s[wave][lg * 4 + r][nt * 16 + l15] = (f16)h;
      }

    // ---- layer 2 ----
    f32x4 out[4];
#pragma unroll
    for (int nt = 0; nt < 4; ++nt) { out[nt][0] = 0.f; out[nt][1] = 0.f; out[nt][2] = 0.f; out[nt][3] = 0.f; }
#pragma unroll
    for (int kk = 0; kk < 2; ++kk) {
      const f16x8 hf = *(const f16x8*)&h1s[wave][l15][kk * 32 + lg * 8];
#pragma unroll
      for (int nt = 0; nt < 4; ++nt) {
        const f16x8 b = *(const f16x8*)&B2s[((kk * 4 + nt) * 64 + lane) * 8];
        out[nt] = mfma16(hf, b, out[nt]);
      }
    }

    // stage ed (bias added) back to LDS rows
#pragma unroll
    for (int nt = 0; nt < 4; ++nt)
#pragma unroll
      for (int r = 0; r < 4; ++r)
        h1s[wave][lg * 4 + r][nt * 16 + l15] = (f16)(out[nt][r] + bias2[nt]);

    // global el write (encoder: fresh; proc: in-place residual; decoder: none)
    const int erA = g * 16 + l15;
    if (STAGE != 2) {
      f16x8 v0 = *(const f16x8*)&h1s[wave][l15][lg * 8];
      f16x8 v1 = *(const f16x8*)&h1s[wave][l15][32 + lg * 8];
      f16* p0 = elw + (size_t)erA * 64 + lg * 8;
      if (STAGE == 1) {
        f16x8 n0, n1;
#pragma unroll
        for (int j = 0; j < 8; ++j) {
          n0[j] = (f16)((float)aCur[4][j] + (float)v0[j]);
          n1[j] = (f16)((float)aCur[5][j] + (float)v1[j]);
        }
        *(f16x8*)p0 = n0;
        *(f16x8*)(p0 + 32) = n1;
      } else {
        *(f16x8*)p0 = v0;
        *(f16x8*)(p0 + 32) = v1;
      }
    }

    // fused segmented reduction: lane = column, walk 16 sorted rows,
    // one coalesced 64-lane atomicAdd per dst segment (dst wave-uniform).
    {
      float racc = 0.f;
      int dprev = __shfl(dA, 0);
#pragma unroll
      for (int row = 0; row < 16; ++row) {
        const int dn = __shfl(dA, row);
        const float v = (float)h1s[wave][row][lane];
        if (dn != dprev) {
          atomicAdd(agg + (size_t)dprev * 64 + lane, racc);
          racc = 0.f;
          dprev = dn;
        }
        racc += v;
      }
      atomicAdd(agg + (size_t)dprev * 64 + lane, racc);
    }

    // rotate pipeline
#pragma unroll
    for (int i = 0; i < NA; ++i) aCur[i] = aNxt[i];
    sA = sB; dA = dB; sB = sC; dB = dC;
  }
}

// ---------------- node MLP (LDS-staged weights, fused mean-finish) ----------------
// STAGE: 0=encoder (A=[x_raw(5,pad32)|agg*inv], out: xl=v, xh=f16(v))
//        1=processor (A=[xh|agg*inv], xl += v, xh mirror)
//        2=decoder   (A=[xh|agg*inv], write d_out[N][7])
template <int STAGE, int KT1, int NT2, int OUTW>
__global__ __launch_bounds__(256, 4)
void node_mlp_kernel(const float* __restrict__ xraw,
                     const f16* xh,
                     const float* __restrict__ agg,
                     const float* __restrict__ inv,
                     const f16* __restrict__ B1,
                     const f16* __restrict__ B2,
                     const float* __restrict__ b1,
                     const float* __restrict__ b2,
                     float* __restrict__ xl,
                     f16* xho,
                     float* __restrict__ outp) {
  constexpr int K1 = KT1 * 32;
  constexpr int NF1 = KT1 * 4;
  constexpr int NF2 = 2 * NT2;
  __shared__ __align__(16) f16 h1s[4][16][72];
  __shared__ __align__(16) f16 B1s[NF1 * 64 * 8];
  __shared__ __align__(16) f16 B2s[NF2 * 64 * 8];
  const int wave = threadIdx.x >> 6;
  const int lane = threadIdx.x & 63;
  const int l15 = lane & 15, lg = lane >> 4;
  const int nwaves = gridDim.x * 4;
  const int wid = blockIdx.x * 4 + wave;
  const int NG = NN / 16;

  for (int f = wave; f < NF1; f += 4) {
    const int kk = f >> 2, nt = f & 3;
    *(f16x8*)&B1s[(f * 64 + lane) * 8] =
        *(const f16x8*)(B1 + (nt * 16 + l15) * K1 + kk * 32 + lg * 8);
  }
  for (int f = wave; f < NF2; f += 4) {
    const int kk = f / NT2, nt = f % NT2;
    *(f16x8*)&B2s[(f * 64 + lane) * 8] =
        *(const f16x8*)(B2 + (nt * 16 + l15) * 64 + kk * 32 + lg * 8);
  }
  float bias1[4], bias2[NT2];
#pragma unroll
  for (int nt = 0; nt < 4; ++nt) bias1[nt] = b1[nt * 16 + l15];
#pragma unroll
  for (int nt = 0; nt < NT2; ++nt) bias2[nt] = (nt * 16 + l15 < OUTW) ? b2[nt * 16 + l15] : 0.f;
  __syncthreads();

  for (int g = wid; g < NG; g += nwaves) {
    const int n0 = g * 16;
    const int rA = n0 + l15;
    const float iv = inv[rA];

    f32x4 acc[4];
#pragma unroll
    for (int nt = 0; nt < 4; ++nt) { acc[nt][0] = 0.f; acc[nt][1] = 0.f; acc[nt][2] = 0.f; acc[nt][3] = 0.f; }

#pragma unroll
    for (int kk = 0; kk < KT1; ++kk) {
      f16x8 a;
      if (STAGE == 0 && kk == 0) {
        a = fzero8();
        if (lg == 0) {
#pragma unroll
          for (int j = 0; j < 5; ++j) a[j] = (f16)xraw[(size_t)rA * 5 + j];
        }
      } else if (STAGE != 0 && kk < 2) {
        a = *(const f16x8*)(xh + (size_t)rA * 64 + kk * 32 + lg * 8);
      } else {
        const int ko = (STAGE == 0) ? (kk - 1) : (kk - 2);
        const float* ap = agg + (size_t)rA * 64 + ko * 32 + lg * 8;
        f32x4 a0 = *(const f32x4*)ap;
        f32x4 a1 = *(const f32x4*)(ap + 4);
#pragma unroll
        for (int j = 0; j < 4; ++j) { a[j] = (f16)(a0[j] * iv); a[4 + j] = (f16)(a1[j] * iv); }
      }
#pragma unroll
      for (int nt = 0; nt < 4; ++nt) {
        const f16x8 b = *(const f16x8*)&B1s[((kk * 4 + nt) * 64 + lane) * 8];
        acc[nt] = mfma16(a, b, acc[nt]);
      }
    }
#pragma unroll
    for (int nt = 0; nt < 4; ++nt)
#pragma unroll
      for (int r = 0; r < 4; ++r) {
        float h = fmaxf(acc[nt][r] + bias1[nt], 0.f);
        h1s[wave][lg * 4 + r][nt * 16 + l15] = (f16)h;
      }

    f32x4 out[NT2];
#pragma unroll
    for (int nt = 0; nt < NT2; ++nt) { out[nt][0] = 0.f; out[nt][1] = 0.f; out[nt][2] = 0.f; out[nt][3] = 0.f; }
#pragma unroll
    for (int kk = 0; kk < 2; ++kk) {
      const f16x8 hf = *(const f16x8*)&h1s[wave][l15][kk * 32 + lg * 8];
#pragma unroll
      for (int nt = 0; nt < NT2; ++nt) {
        const f16x8 b = *(const f16x8*)&B2s[((kk * NT2 + nt) * 64 + lane) * 8];
        out[nt] = mfma16(hf, b, out[nt]);
      }
    }
#pragma unroll
    for (int r = 0; r < 4; ++r) {
      const int row = n0 + lg * 4 + r;
#pragma unroll
      for (int nt = 0; nt < NT2; ++nt) {
        const int col = nt * 16 + l15;
        float v = out[nt][r] + bias2[nt];
        if (STAGE == 0) {
          xl[(size_t)row * 64 + col] = v;
          xho[(size_t)row * 64 + col] = (f16)v;
        } else if (STAGE == 1) {
          float nv = xl[(size_t)row * 64 + col] + v;
          xl[(size_t)row * 64 + col] = nv;
          xho[(size_t)row * 64 + col] = (f16)nv;
        } else {
          if (col < OUTW) outp[(size_t)row * OUTW + col] = v;
        }
      }
    }
  }
}

// ---------------- launch ----------------

extern "C" void kernel_launch(void* const* d_in, const int* in_sizes, int n_in,
                              void* d_out, int out_size, void* d_ws, size_t ws_size,
                              hipStream_t stream) {
  const float* x  = (const float*)d_in[0];
  const int* ei   = (const int*)d_in[1];
  const float* ea = (const float*)d_in[2];
  const float* enc_e_b1 = (const float*)d_in[4];
  const float* enc_e_b2 = (const float*)d_in[6];
  const float* enc_n_b1 = (const float*)d_in[8];
  const float* enc_n_b2 = (const float*)d_in[10];
  const float* proc_e_b1 = (const float*)d_in[12];
  const float* proc_e_b2 = (const float*)d_in[14];
  const float* proc_n_b1 = (const float*)d_in[16];
  const float* proc_n_b2 = (const float*)d_in[18];
  const float* dec_e_b1 = (const float*)d_in[20];
  const float* dec_e_b2 = (const float*)d_in[22];
  const float* dec_n_b1 = (const float*)d_in[24];
  const float* dec_n_b2 = (const float*)d_in[26];

  const int* src = ei;
  const int* dst = ei + NE;

  // workspace layout (~167 MB total; R2 proved >= 263 MB available)
  char* p = (char*)d_ws;
  f16* el    = (f16*)p;   p += (size_t)NE * 64 * 2;   // 102.4 MB
  f16* Aenc  = (f16*)p;   p += (size_t)NE * 16 * 2;   // 25.6 MB
  float* xl  = (float*)p; p += (size_t)NN * 64 * 4;   // 12.8 MB
  f16* xh    = (f16*)p;   p += (size_t)NN * 64 * 2;   // 6.4 MB
  float* agg = (float*)p; p += (size_t)NN * 64 * 4;   // 12.8 MB f32 atomic accumulator
  int* cnt   = (int*)p;   p += (size_t)NN * 4;
  int* off   = (int*)p;   p += (size_t)(NN + 1) * 4;
  int* cur   = (int*)p;   p += (size_t)NN * 4;
  float* inv = (float*)p; p += (size_t)NN * 4;
  int* psrc  = (int*)p;   p += (size_t)NE * 4;
  int* pdst  = (int*)p;   p += (size_t)NE * 4;
  f16* wb    = (f16*)p;   p += 70656 * 2;
  f16* W1T_ence = wb + 0;
  f16* W2T_ence = wb + 2048;
  f16* W1T_encn = wb + 6144;
  f16* W2T_encn = wb + 12288;
  f16* W1T_proce = wb + 16384;
  f16* W2T_proce = wb + 28672;
  f16* W1T_procn = wb + 32768;
  f16* W2T_procn = wb + 40960;
  f16* W1T_dece = wb + 45056;
  f16* W2T_dece = wb + 57344;
  f16* W1T_decn = wb + 61440;
  f16* W2T_decn = wb + 69632;

  hipMemsetAsync(cnt, 0, (size_t)NN * 4, stream);
  hipMemsetAsync(wb, 0, 70656 * 2, stream);

  count_kernel<<<(NE + 255) / 256, 256, 0, stream>>>(dst, cnt);
  scan_kernel<<<1, 1024, 0, stream>>>(cnt, off, cur, inv);
  scatter_pack<<<(NE + 255) / 256, 256, 0, stream>>>(x, ea, src, dst, cur, psrc, pdst, Aenc);

  PrepPtrs P;
  P.W[0]  = (const float*)d_in[3];   // enc_e_w1
  P.W[1]  = (const float*)d_in[5];   // enc_e_w2
  P.W[2]  = (const float*)d_in[7];   // enc_n_w1 (raw part)
  P.W[3]  = (const float*)d_in[7];   // enc_n_w1 (agg part)
  P.W[4]  = (const float*)d_in[9];   // enc_n_w2
  P.W[5]  = (const float*)d_in[11];  // proc_e_w1
  P.W[6]  = (const float*)d_in[13];  // proc_e_w2
  P.W[7]  = (const float*)d_in[15];  // proc_n_w1
  P.W[8]  = (const float*)d_in[17];  // proc_n_w2
  P.W[9]  = (const float*)d_in[19];  // dec_e_w1
  P.W[10] = (const float*)d_in[21];  // dec_e_w2
  P.W[11] = (const float*)d_in[23];  // dec_n_w1
  P.W[12] = (const float*)d_in[25];  // dec_n_w2
  prep_all<<<13, 256, 0, stream>>>(P, wb);

  const int EDGE_BLK = 1024;  // 512-thread blocks, 8192 waves total
  const size_t AGG_BYTES = (size_t)NN * 64 * 4;

  // ---- encoder ----
  hipMemsetAsync(agg, 0, AGG_BYTES, stream);
  edge_mlp_kernel<0, 1><<<EDGE_BLK, 512, 0, stream>>>(Aenc, xh, el, el, psrc, pdst,
                                                      W1T_ence, W2T_ence, enc_e_b1, enc_e_b2, agg);
  node_mlp_kernel<0, 3, 4, 64><<<256, 256, 0, stream>>>(x, xh, agg, inv, W1T_encn, W2T_encn,
                                                        enc_n_b1, enc_n_b2, xl, xh, (float*)d_out);
  // ---- 2 processor rounds (shared weights, residuals) ----
  for (int r = 0; r < 2; ++r) {
    hipMemsetAsync(agg, 0, AGG_BYTES, stream);
    edge_mlp_kernel<1, 6><<<EDGE_BLK, 512, 0, stream>>>(Aenc, xh, el, el, psrc, pdst,
                                                        W1T_proce, W2T_proce, proc_e_b1, proc_e_b2, agg);
    node_mlp_kernel<1, 4, 4, 64><<<256, 256, 0, stream>>>(x, xh, agg, inv, W1T_procn, W2T_procn,
                                                          proc_n_b1, proc_n_b2, xl, xh, (float*)d_out);
  }
  // ---- decoder (no el write; agg of ed only) ----
  hipMemsetAsync(agg, 0, AGG_BYTES, stream);
  edge_mlp_kernel<2, 6><<<EDGE_BLK, 512, 0, stream>>>(Aenc, xh, el, el, psrc, pdst,
                                                      W1T_dece, W2T_dece, dec_e_b1, dec_e_b2, agg);
  node_mlp_kernel<2, 4, 1, 7><<<256, 256, 0, stream>>>(x, xh, agg, inv, W1T_decn, W2T_decn,
                                                       dec_n_b1, dec_n_b2, xl, xh, (float*)d_out);
}

// Round 13
// 693.154 us; speedup vs baseline: 1.6493x; 1.1066x over previous
//
#include <hip/hip_runtime.h>

#define NN 50000
#define NE 800000

typedef _Float16 f16;
typedef _Float16 f16x8 __attribute__((ext_vector_type(8)));
typedef float f32x4 __attribute__((ext_vector_type(4)));

__device__ __forceinline__ f16x8 fzero8() {
  f16x8 v;
#pragma unroll
  for (int i = 0; i < 8; ++i) v[i] = (f16)0.f;
  return v;
}

__device__ __forceinline__ f32x4 mfma16(f16x8 a, f16x8 b, f32x4 c) {
  return __builtin_amdgcn_mfma_f32_16x16x32_f16(a, b, c, 0, 0, 0);
}

// ---------------- prep kernels ----------------

__global__ void count_kernel(const int* __restrict__ dst, int* __restrict__ cnt) {
  int e = blockIdx.x * 256 + threadIdx.x;
  if (e < NE) atomicAdd(&cnt[dst[e]], 1);
}

// single-block exclusive scan over cnt -> off/cur, plus inv = 1/max(cnt,1)
__global__ void scan_kernel(const int* __restrict__ cnt, int* __restrict__ off,
                            int* __restrict__ cur, float* __restrict__ inv) {
  __shared__ int part[1024];
  const int t = threadIdx.x;
  const int CH = (NN + 1023) / 1024;
  const int i0 = t * CH, i1 = (i0 + CH < NN) ? i0 + CH : NN;
  int s = 0;
  for (int i = i0; i < i1; ++i) s += cnt[i];
  part[t] = s;
  __syncthreads();
  for (int d = 1; d < 1024; d <<= 1) {
    int v = (t >= d) ? part[t - d] : 0;
    __syncthreads();
    part[t] += v;
    __syncthreads();
  }
  int base = (t > 0) ? part[t - 1] : 0;
  for (int i = i0; i < i1; ++i) {
    off[i] = base;
    cur[i] = base;
    inv[i] = 1.0f / fmaxf((float)cnt[i], 1.0f);
    base += cnt[i];
  }
  if (t == 1023) off[NN] = NE;
}

// scatter edges into dst-sorted order; also build packed encoder rows
__global__ void scatter_pack(const float* __restrict__ x, const float* __restrict__ ea,
                             const int* __restrict__ src, const int* __restrict__ dst,
                             int* __restrict__ cur, int* __restrict__ psrc,
                             int* __restrict__ pdst, f16* __restrict__ A) {
  int e = blockIdx.x * 256 + threadIdx.x;
  if (e >= NE) return;
  int s = src[e], d = dst[e];
  int pos = atomicAdd(&cur[d], 1);
  psrc[pos] = s;
  pdst[pos] = d;
  f16 row[16];
#pragma unroll
  for (int i = 0; i < 5; ++i) { row[i] = (f16)x[s * 5 + i]; row[5 + i] = (f16)x[d * 5 + i]; }
#pragma unroll
  for (int i = 0; i < 4; ++i) row[10 + i] = (f16)ea[e * 4 + i];
  row[14] = (f16)0.f; row[15] = (f16)0.f;
  *(f16x8*)(A + (size_t)pos * 16) = *(f16x8*)row;
  *(f16x8*)(A + (size_t)pos * 16 + 8) = *(f16x8*)(row + 8);
}

// all 13 weight transposes in one launch; block b handles matrix b
struct PrepPtrs { const float* W[13]; };
__global__ void prep_all(PrepPtrs P, f16* __restrict__ out) {
  const int Nw[13]   = {64,64,64,64,64,64,64,64,64,64,64,64,7};
  const int Kd[13]   = {32,64,96,96,64,192,64,128,64,192,64,128,64};
  const int ks[13]   = {0,0,0,5,0,0,0,0,0,0,0,0,0};
  const int kd[13]   = {0,0,0,32,0,0,0,0,0,0,0,0,0};
  const int klen[13] = {14,64,5,64,64,192,64,128,64,192,64,128,64};
  const int nc[13]   = {64,64,64,64,64,64,64,64,64,64,64,64,7};
  const int ofs[13]  = {0,2048,6144,6144,12288,16384,28672,32768,40960,45056,57344,61440,69632};
  const int m = blockIdx.x;
  const float* W = P.W[m];
  const int tot = klen[m] * nc[m];
  for (int idx = threadIdx.x; idx < tot; idx += 256) {
    int kk = idx / nc[m], n = idx % nc[m];
    out[ofs[m] + n * Kd[m] + kd[m] + kk] = (f16)W[(ks[m] + kk) * Nw[m] + n];
  }
}

// ---------------- edge MLP (R7 structure + XCD-partitioned group mapping) ----------------
// blockIdx & 7 selects the XCD; each XCD owns a contiguous dst-sorted group range
// -> dst gathers, el stream, idx stream, and agg atomics become XCD-L2-local.
// STAGE: 0=encoder (A from packed Aenc, write el, agg += el)
//        1=processor (A=[xh[src]|xh[dst]|el], el += ed in place, agg += ed)
//        2=decoder   (A same as proc, NO el write, agg += ed)
template <int STAGE, int KT1>
__global__ __launch_bounds__(256, 3)
void edge_mlp_kernel(const f16* __restrict__ Aenc,
                     const f16* __restrict__ xh,
                     const f16* elr, f16* elw,
                     const int* __restrict__ psrc,
                     const int* __restrict__ pdst,
                     const f16* __restrict__ B1,
                     const f16* __restrict__ B2,
                     const float* __restrict__ b1,
                     const float* __restrict__ b2,
                     float* __restrict__ agg) {
  constexpr int K1 = KT1 * 32;
  constexpr int NF1 = KT1 * 4;              // L1 fragment count
  constexpr int NA = (STAGE == 0) ? 1 : 6;  // A fragments per group
  __shared__ __align__(16) f16 h1s[4][16][72];    // 9216 B
  __shared__ __align__(16) f16 B1s[NF1 * 64 * 8]; // KT1=6: 24576 B
  __shared__ __align__(16) f16 B2s[8 * 64 * 8];   // 8192 B  (total 41984 -> 3 blk/CU)

  const int wave = threadIdx.x >> 6;
  const int lane = threadIdx.x & 63;
  const int l15 = lane & 15, lg = lane >> 4;
  const int NG = NE / 16;

  // XCD-partitioned mapping: 8 partitions of NG/8 contiguous groups
  const int xcd = blockIdx.x & 7;
  const int wlocal = (blockIdx.x >> 3) * 4 + wave;   // wave id within partition
  const int WPP = (gridDim.x >> 3) * 4;              // waves per partition
  const int NGP = NG >> 3;                           // groups per partition
  const int gBase = xcd * NGP;
  const int gEnd = gBase + NGP;

  // ---- stage weight fragments into LDS (fragment-major, conflict-free reads) ----
  for (int f = wave; f < NF1; f += 4) {
    const int kk = f >> 2, nt = f & 3;
    *(f16x8*)&B1s[(f * 64 + lane) * 8] =
        *(const f16x8*)(B1 + (nt * 16 + l15) * K1 + kk * 32 + lg * 8);
  }
  for (int f = wave; f < 8; f += 4) {
    const int kk = f >> 2, nt = f & 3;
    *(f16x8*)&B2s[(f * 64 + lane) * 8] =
        *(const f16x8*)(B2 + (nt * 16 + l15) * 64 + kk * 32 + lg * 8);
  }
  float bias1[4], bias2[4];
#pragma unroll
  for (int nt = 0; nt < 4; ++nt) { bias1[nt] = b1[nt * 16 + l15]; bias2[nt] = b2[nt * 16 + l15]; }
  __syncthreads();

  // ---- A-fragment loader ----
  auto loadA = [&](int g, int s, int d, f16x8* a) {
    const int erA = g * 16 + l15;
    if (STAGE == 0) {
      a[0] = fzero8();
      if (lg < 2) a[0] = *(const f16x8*)(Aenc + (size_t)erA * 16 + lg * 8);
    } else {
      a[0] = *(const f16x8*)(xh + (size_t)s * 64 + lg * 8);
      a[1] = *(const f16x8*)(xh + (size_t)s * 64 + 32 + lg * 8);
      a[2] = *(const f16x8*)(xh + (size_t)d * 64 + lg * 8);
      a[3] = *(const f16x8*)(xh + (size_t)d * 64 + 32 + lg * 8);
      a[4] = *(const f16x8*)(elr + (size_t)erA * 64 + lg * 8);
      a[5] = *(const f16x8*)(elr + (size_t)erA * 64 + 32 + lg * 8);
    }
  };

  // ---- software pipeline: idx 2-deep, A-frags 1-deep (R7-proven) ----
  const int g1 = gBase + wlocal;
  int sA = 0, dA = 0, sB = 0, dB = 0;
  dA = pdst[g1 * 16 + l15];
  if (STAGE != 0) sA = psrc[g1 * 16 + l15];
  f16x8 aCur[NA], aNxt[NA];
  loadA(g1, sA, dA, aCur);
  {
    const int g2 = g1 + WPP;
    if (g2 < gEnd) {
      dB = pdst[g2 * 16 + l15];
      if (STAGE != 0) sB = psrc[g2 * 16 + l15];
    }
  }

  for (int g = g1; g < gEnd; g += WPP) {
    const int gN = g + WPP;
    if (gN < gEnd) loadA(gN, sB, dB, aNxt);        // prefetch next group's A
    int sC = 0, dC = 0;
    const int g3 = g + 2 * WPP;
    if (g3 < gEnd) {                                // prefetch idx 2 ahead
      dC = pdst[g3 * 16 + l15];
      if (STAGE != 0) sC = psrc[g3 * 16 + l15];
    }

    // ---- layer 1: MFMA with LDS B-frags ----
    f32x4 acc[4];
#pragma unroll
    for (int nt = 0; nt < 4; ++nt) { acc[nt][0] = 0.f; acc[nt][1] = 0.f; acc[nt][2] = 0.f; acc[nt][3] = 0.f; }
#pragma unroll
    for (int kk = 0; kk < KT1; ++kk) {
      const f16x8 a = aCur[(STAGE == 0) ? 0 : kk];
#pragma unroll
      for (int nt = 0; nt < 4; ++nt) {
        const f16x8 b = *(const f16x8*)&B1s[((kk * 4 + nt) * 64 + lane) * 8];
        acc[nt] = mfma16(a, b, acc[nt]);
      }
    }
    // bias + relu, stage h1 to LDS (C-layout -> A-layout); per-wave slice
#pragma unroll
    for (int nt = 0; nt < 4; ++nt)
#pragma unroll
      for (int r = 0; r < 4; ++r) {
        float h = fmaxf(acc[nt][r] + bias1[nt], 0.f);
        h1s[wave][lg * 4 + r][nt * 16 + l15] = (f16)h;
      }

    // ---- layer 2 ----
    f32x4 out[4];
#pragma unroll
    for (int nt = 0; nt < 4; ++nt) { out[nt][0] = 0.f; out[nt][1] = 0.f; out[nt][2] = 0.f; out[nt][3] = 0.f; }
#pragma unroll
    for (int kk = 0; kk < 2; ++kk) {
      const f16x8 hf = *(const f16x8*)&h1s[wave][l15][kk * 32 + lg * 8];
#pragma unroll
      for (int nt = 0; nt < 4; ++nt) {
        const f16x8 b = *(const f16x8*)&B2s[((kk * 4 + nt) * 64 + lane) * 8];
        out[nt] = mfma16(hf, b, out[nt]);
      }
    }

    // stage ed (bias added) back to LDS rows
#pragma unroll
    for (int nt = 0; nt < 4; ++nt)
#pragma unroll
      for (int r = 0; r < 4; ++r)
        h1s[wave][lg * 4 + r][nt * 16 + l15] = (f16)(out[nt][r] + bias2[nt]);

    // global el write (encoder: fresh; proc: in-place residual; decoder: none)
    const int erA = g * 16 + l15;
    if (STAGE != 2) {
      f16x8 v0 = *(const f16x8*)&h1s[wave][l15][lg * 8];
      f16x8 v1 = *(const f16x8*)&h1s[wave][l15][32 + lg * 8];
      f16* p0 = elw + (size_t)erA * 64 + lg * 8;
      if (STAGE == 1) {
        f16x8 n0, n1;
#pragma unroll
        for (int j = 0; j < 8; ++j) {
          n0[j] = (f16)((float)aCur[4][j] + (float)v0[j]);
          n1[j] = (f16)((float)aCur[5][j] + (float)v1[j]);
        }
        *(f16x8*)p0 = n0;
        *(f16x8*)(p0 + 32) = n1;
      } else {
        *(f16x8*)p0 = v0;
        *(f16x8*)(p0 + 32) = v1;
      }
    }

    // fused segmented reduction: lane = column, walk 16 sorted rows,
    // one coalesced 64-lane atomicAdd per dst segment (dst wave-uniform).
    {
      float racc = 0.f;
      int dprev = __shfl(dA, 0);
#pragma unroll
      for (int row = 0; row < 16; ++row) {
        const int dn = __shfl(dA, row);
        const float v = (float)h1s[wave][row][lane];
        if (dn != dprev) {
          atomicAdd(agg + (size_t)dprev * 64 + lane, racc);
          racc = 0.f;
          dprev = dn;
        }
        racc += v;
      }
      atomicAdd(agg + (size_t)dprev * 64 + lane, racc);
    }

    // rotate pipeline
#pragma unroll
    for (int i = 0; i < NA; ++i) aCur[i] = aNxt[i];
    sA = sB; dA = dB; sB = sC; dB = dC;
  }
}

// ---------------- node MLP (LDS-staged weights, fused mean-finish) ----------------
// STAGE: 0=encoder (A=[x_raw(5,pad32)|agg*inv], out: xl=v, xh=f16(v))
//        1=processor (A=[xh|agg*inv], xl += v, xh mirror)
//        2=decoder   (A=[xh|agg*inv], write d_out[N][7])
template <int STAGE, int KT1, int NT2, int OUTW>
__global__ __launch_bounds__(256, 4)
void node_mlp_kernel(const float* __restrict__ xraw,
                     const f16* xh,
                     const float* __restrict__ agg,
                     const float* __restrict__ inv,
                     const f16* __restrict__ B1,
                     const f16* __restrict__ B2,
                     const float* __restrict__ b1,
                     const float* __restrict__ b2,
                     float* __restrict__ xl,
                     f16* xho,
                     float* __restrict__ outp) {
  constexpr int K1 = KT1 * 32;
  constexpr int NF1 = KT1 * 4;
  constexpr int NF2 = 2 * NT2;
  __shared__ __align__(16) f16 h1s[4][16][72];
  __shared__ __align__(16) f16 B1s[NF1 * 64 * 8];
  __shared__ __align__(16) f16 B2s[NF2 * 64 * 8];
  const int wave = threadIdx.x >> 6;
  const int lane = threadIdx.x & 63;
  const int l15 = lane & 15, lg = lane >> 4;
  const int nwaves = gridDim.x * 4;
  const int wid = blockIdx.x * 4 + wave;
  const int NG = NN / 16;

  for (int f = wave; f < NF1; f += 4) {
    const int kk = f >> 2, nt = f & 3;
    *(f16x8*)&B1s[(f * 64 + lane) * 8] =
        *(const f16x8*)(B1 + (nt * 16 + l15) * K1 + kk * 32 + lg * 8);
  }
  for (int f = wave; f < NF2; f += 4) {
    const int kk = f / NT2, nt = f % NT2;
    *(f16x8*)&B2s[(f * 64 + lane) * 8] =
        *(const f16x8*)(B2 + (nt * 16 + l15) * 64 + kk * 32 + lg * 8);
  }
  float bias1[4], bias2[NT2];
#pragma unroll
  for (int nt = 0; nt < 4; ++nt) bias1[nt] = b1[nt * 16 + l15];
#pragma unroll
  for (int nt = 0; nt < NT2; ++nt) bias2[nt] = (nt * 16 + l15 < OUTW) ? b2[nt * 16 + l15] : 0.f;
  __syncthreads();

  for (int g = wid; g < NG; g += nwaves) {
    const int n0 = g * 16;
    const int rA = n0 + l15;
    const float iv = inv[rA];

    f32x4 acc[4];
#pragma unroll
    for (int nt = 0; nt < 4; ++nt) { acc[nt][0] = 0.f; acc[nt][1] = 0.f; acc[nt][2] = 0.f; acc[nt][3] = 0.f; }

#pragma unroll
    for (int kk = 0; kk < KT1; ++kk) {
      f16x8 a;
      if (STAGE == 0 && kk == 0) {
        a = fzero8();
        if (lg == 0) {
#pragma unroll
          for (int j = 0; j < 5; ++j) a[j] = (f16)xraw[(size_t)rA * 5 + j];
        }
      } else if (STAGE != 0 && kk < 2) {
        a = *(const f16x8*)(xh + (size_t)rA * 64 + kk * 32 + lg * 8);
      } else {
        const int ko = (STAGE == 0) ? (kk - 1) : (kk - 2);
        const float* ap = agg + (size_t)rA * 64 + ko * 32 + lg * 8;
        f32x4 a0 = *(const f32x4*)ap;
        f32x4 a1 = *(const f32x4*)(ap + 4);
#pragma unroll
        for (int j = 0; j < 4; ++j) { a[j] = (f16)(a0[j] * iv); a[4 + j] = (f16)(a1[j] * iv); }
      }
#pragma unroll
      for (int nt = 0; nt < 4; ++nt) {
        const f16x8 b = *(const f16x8*)&B1s[((kk * 4 + nt) * 64 + lane) * 8];
        acc[nt] = mfma16(a, b, acc[nt]);
      }
    }
#pragma unroll
    for (int nt = 0; nt < 4; ++nt)
#pragma unroll
      for (int r = 0; r < 4; ++r) {
        float h = fmaxf(acc[nt][r] + bias1[nt], 0.f);
        h1s[wave][lg * 4 + r][nt * 16 + l15] = (f16)h;
      }

    f32x4 out[NT2];
#pragma unroll
    for (int nt = 0; nt < NT2; ++nt) { out[nt][0] = 0.f; out[nt][1] = 0.f; out[nt][2] = 0.f; out[nt][3] = 0.f; }
#pragma unroll
    for (int kk = 0; kk < 2; ++kk) {
      const f16x8 hf = *(const f16x8*)&h1s[wave][l15][kk * 32 + lg * 8];
#pragma unroll
      for (int nt = 0; nt < NT2; ++nt) {
        const f16x8 b = *(const f16x8*)&B2s[((kk * NT2 + nt) * 64 + lane) * 8];
        out[nt] = mfma16(hf, b, out[nt]);
      }
    }
#pragma unroll
    for (int r = 0; r < 4; ++r) {
      const int row = n0 + lg * 4 + r;
#pragma unroll
      for (int nt = 0; nt < NT2; ++nt) {
        const int col = nt * 16 + l15;
        float v = out[nt][r] + bias2[nt];
        if (STAGE == 0) {
          xl[(size_t)row * 64 + col] = v;
          xho[(size_t)row * 64 + col] = (f16)v;
        } else if (STAGE == 1) {
          float nv = xl[(size_t)row * 64 + col] + v;
          xl[(size_t)row * 64 + col] = nv;
          xho[(size_t)row * 64 + col] = (f16)nv;
        } else {
          if (col < OUTW) outp[(size_t)row * OUTW + col] = v;
        }
      }
    }
  }
}

// ---------------- launch ----------------

extern "C" void kernel_launch(void* const* d_in, const int* in_sizes, int n_in,
                              void* d_out, int out_size, void* d_ws, size_t ws_size,
                              hipStream_t stream) {
  const float* x  = (const float*)d_in[0];
  const int* ei   = (const int*)d_in[1];
  const float* ea = (const float*)d_in[2];
  const float* enc_e_b1 = (const float*)d_in[4];
  const float* enc_e_b2 = (const float*)d_in[6];
  const float* enc_n_b1 = (const float*)d_in[8];
  const float* enc_n_b2 = (const float*)d_in[10];
  const float* proc_e_b1 = (const float*)d_in[12];
  const float* proc_e_b2 = (const float*)d_in[14];
  const float* proc_n_b1 = (const float*)d_in[16];
  const float* proc_n_b2 = (const float*)d_in[18];
  const float* dec_e_b1 = (const float*)d_in[20];
  const float* dec_e_b2 = (const float*)d_in[22];
  const float* dec_n_b1 = (const float*)d_in[24];
  const float* dec_n_b2 = (const float*)d_in[26];

  const int* src = ei;
  const int* dst = ei + NE;

  // workspace layout (~167 MB total; R2 proved >= 263 MB available)
  char* p = (char*)d_ws;
  f16* el    = (f16*)p;   p += (size_t)NE * 64 * 2;   // 102.4 MB
  f16* Aenc  = (f16*)p;   p += (size_t)NE * 16 * 2;   // 25.6 MB
  float* xl  = (float*)p; p += (size_t)NN * 64 * 4;   // 12.8 MB
  f16* xh    = (f16*)p;   p += (size_t)NN * 64 * 2;   // 6.4 MB
  float* agg = (float*)p; p += (size_t)NN * 64 * 4;   // 12.8 MB f32 atomic accumulator
  int* cnt   = (int*)p;   p += (size_t)NN * 4;
  int* off   = (int*)p;   p += (size_t)(NN + 1) * 4;
  int* cur   = (int*)p;   p += (size_t)NN * 4;
  float* inv = (float*)p; p += (size_t)NN * 4;
  int* psrc  = (int*)p;   p += (size_t)NE * 4;
  int* pdst  = (int*)p;   p += (size_t)NE * 4;
  f16* wb    = (f16*)p;   p += 70656 * 2;
  f16* W1T_ence = wb + 0;
  f16* W2T_ence = wb + 2048;
  f16* W1T_encn = wb + 6144;
  f16* W2T_encn = wb + 12288;
  f16* W1T_proce = wb + 16384;
  f16* W2T_proce = wb + 28672;
  f16* W1T_procn = wb + 32768;
  f16* W2T_procn = wb + 40960;
  f16* W1T_dece = wb + 45056;
  f16* W2T_dece = wb + 57344;
  f16* W1T_decn = wb + 61440;
  f16* W2T_decn = wb + 69632;

  hipMemsetAsync(cnt, 0, (size_t)NN * 4, stream);
  hipMemsetAsync(wb, 0, 70656 * 2, stream);

  count_kernel<<<(NE + 255) / 256, 256, 0, stream>>>(dst, cnt);
  scan_kernel<<<1, 1024, 0, stream>>>(cnt, off, cur, inv);
  scatter_pack<<<(NE + 255) / 256, 256, 0, stream>>>(x, ea, src, dst, cur, psrc, pdst, Aenc);

  PrepPtrs P;
  P.W[0]  = (const float*)d_in[3];   // enc_e_w1
  P.W[1]  = (const float*)d_in[5];   // enc_e_w2
  P.W[2]  = (const float*)d_in[7];   // enc_n_w1 (raw part)
  P.W[3]  = (const float*)d_in[7];   // enc_n_w1 (agg part)
  P.W[4]  = (const float*)d_in[9];   // enc_n_w2
  P.W[5]  = (const float*)d_in[11];  // proc_e_w1
  P.W[6]  = (const float*)d_in[13];  // proc_e_w2
  P.W[7]  = (const float*)d_in[15];  // proc_n_w1
  P.W[8]  = (const float*)d_in[17];  // proc_n_w2
  P.W[9]  = (const float*)d_in[19];  // dec_e_w1
  P.W[10] = (const float*)d_in[21];  // dec_e_w2
  P.W[11] = (const float*)d_in[23];  // dec_n_w1
  P.W[12] = (const float*)d_in[25];  // dec_n_w2
  prep_all<<<13, 256, 0, stream>>>(P, wb);

  // 768 blocks = 96 per XCD = exactly 3 resident blocks/CU; XCD-partitioned mapping
  const int EDGE_BLK = 768;
  const size_t AGG_BYTES = (size_t)NN * 64 * 4;

  // ---- encoder ----
  hipMemsetAsync(agg, 0, AGG_BYTES, stream);
  edge_mlp_kernel<0, 1><<<EDGE_BLK, 256, 0, stream>>>(Aenc, xh, el, el, psrc, pdst,
                                                      W1T_ence, W2T_ence, enc_e_b1, enc_e_b2, agg);
  node_mlp_kernel<0, 3, 4, 64><<<256, 256, 0, stream>>>(x, xh, agg, inv, W1T_encn, W2T_encn,
                                                        enc_n_b1, enc_n_b2, xl, xh, (float*)d_out);
  // ---- 2 processor rounds (shared weights, residuals) ----
  for (int r = 0; r < 2; ++r) {
    hipMemsetAsync(agg, 0, AGG_BYTES, stream);
    edge_mlp_kernel<1, 6><<<EDGE_BLK, 256, 0, stream>>>(Aenc, xh, el, el, psrc, pdst,
                                                        W1T_proce, W2T_proce, proc_e_b1, proc_e_b2, agg);
    node_mlp_kernel<1, 4, 4, 64><<<256, 256, 0, stream>>>(x, xh, agg, inv, W1T_procn, W2T_procn,
                                                          proc_n_b1, proc_n_b2, xl, xh, (float*)d_out);
  }
  // ---- decoder (no el write; agg of ed only) ----
  hipMemsetAsync(agg, 0, AGG_BYTES, stream);
  edge_mlp_kernel<2, 6><<<EDGE_BLK, 256, 0, stream>>>(Aenc, xh, el, el, psrc, pdst,
                                                      W1T_dece, W2T_dece, dec_e_b1, dec_e_b2, agg);
  node_mlp_kernel<2, 4, 1, 7><<<256, 256, 0, stream>>>(x, xh, agg, inv, W1T_decn, W2T_decn,
                                                       dec_n_b1, dec_n_b2, xl, xh, (float*)d_out);
}

// Round 15
// 691.545 us; speedup vs baseline: 1.6531x; 1.0023x over previous
//
#include <hip/hip_runtime.h>

#define NN 50000
#define NE 800000

typedef _Float16 f16;
typedef _Float16 f16x8 __attribute__((ext_vector_type(8)));
typedef float f32x4 __attribute__((ext_vector_type(4)));
typedef float f32x2 __attribute__((ext_vector_type(2)));

__device__ __forceinline__ f16x8 fzero8() {
  f16x8 v;
#pragma unroll
  for (int i = 0; i < 8; ++i) v[i] = (f16)0.f;
  return v;
}

__device__ __forceinline__ f32x4 mfma16(f16x8 a, f16x8 b, f32x4 c) {
  return __builtin_amdgcn_mfma_f32_16x16x32_f16(a, b, c, 0, 0, 0);
}

// decode 8 packed fp8(e4m3, native gfx950) -> f16x8 via HW cvt + scalar f32->f16
__device__ __forceinline__ f16x8 dec8(uint2 q) {
  f32x2 f0 = __builtin_amdgcn_cvt_pk_f32_fp8(q.x, false);
  f32x2 f1 = __builtin_amdgcn_cvt_pk_f32_fp8(q.x, true);
  f32x2 f2 = __builtin_amdgcn_cvt_pk_f32_fp8(q.y, false);
  f32x2 f3 = __builtin_amdgcn_cvt_pk_f32_fp8(q.y, true);
  f16x8 r;
  r[0] = (f16)f0[0]; r[1] = (f16)f0[1];
  r[2] = (f16)f1[0]; r[3] = (f16)f1[1];
  r[4] = (f16)f2[0]; r[5] = (f16)f2[1];
  r[6] = (f16)f3[0]; r[7] = (f16)f3[1];
  return r;
}

// ---------------- prep kernels ----------------

__global__ void count_kernel(const int* __restrict__ dst, int* __restrict__ cnt) {
  int e = blockIdx.x * 256 + threadIdx.x;
  if (e < NE) atomicAdd(&cnt[dst[e]], 1);
}

// single-block exclusive scan over cnt -> off/cur, plus inv = 1/max(cnt,1)
__global__ void scan_kernel(const int* __restrict__ cnt, int* __restrict__ off,
                            int* __restrict__ cur, float* __restrict__ inv) {
  __shared__ int part[1024];
  const int t = threadIdx.x;
  const int CH = (NN + 1023) / 1024;
  const int i0 = t * CH, i1 = (i0 + CH < NN) ? i0 + CH : NN;
  int s = 0;
  for (int i = i0; i < i1; ++i) s += cnt[i];
  part[t] = s;
  __syncthreads();
  for (int d = 1; d < 1024; d <<= 1) {
    int v = (t >= d) ? part[t - d] : 0;
    __syncthreads();
    part[t] += v;
    __syncthreads();
  }
  int base = (t > 0) ? part[t - 1] : 0;
  for (int i = i0; i < i1; ++i) {
    off[i] = base;
    cur[i] = base;
    inv[i] = 1.0f / fmaxf((float)cnt[i], 1.0f);
    base += cnt[i];
  }
  if (t == 1023) off[NN] = NE;
}

// scatter edges into dst-sorted order; also build packed encoder rows
__global__ void scatter_pack(const float* __restrict__ x, const float* __restrict__ ea,
                             const int* __restrict__ src, const int* __restrict__ dst,
                             int* __restrict__ cur, int* __restrict__ psrc,
                             int* __restrict__ pdst, f16* __restrict__ A) {
  int e = blockIdx.x * 256 + threadIdx.x;
  if (e >= NE) return;
  int s = src[e], d = dst[e];
  int pos = atomicAdd(&cur[d], 1);
  psrc[pos] = s;
  pdst[pos] = d;
  f16 row[16];
#pragma unroll
  for (int i = 0; i < 5; ++i) { row[i] = (f16)x[s * 5 + i]; row[5 + i] = (f16)x[d * 5 + i]; }
#pragma unroll
  for (int i = 0; i < 4; ++i) row[10 + i] = (f16)ea[e * 4 + i];
  row[14] = (f16)0.f; row[15] = (f16)0.f;
  *(f16x8*)(A + (size_t)pos * 16) = *(f16x8*)row;
  *(f16x8*)(A + (size_t)pos * 16 + 8) = *(f16x8*)(row + 8);
}

// f16 xh -> fp8 gather mirror xq (3.2 MB, fits a 4MB XCD L2)
__global__ void xq_kernel(const f16* __restrict__ xh, unsigned char* __restrict__ xq) {
  int i = blockIdx.x * 256 + threadIdx.x;  // over NN*8 rows of 8 elems
  if (i >= NN * 8) return;
  f16x8 v = *(const f16x8*)(xh + (size_t)i * 8);
  unsigned lo = 0, hi = 0;
  lo = __builtin_amdgcn_cvt_pk_fp8_f32((float)v[0], (float)v[1], lo, false);
  lo = __builtin_amdgcn_cvt_pk_fp8_f32((float)v[2], (float)v[3], lo, true);
  hi = __builtin_amdgcn_cvt_pk_fp8_f32((float)v[4], (float)v[5], hi, false);
  hi = __builtin_amdgcn_cvt_pk_fp8_f32((float)v[6], (float)v[7], hi, true);
  uint2 q; q.x = lo; q.y = hi;
  *(uint2*)(xq + (size_t)i * 8) = q;
}

// all 13 weight transposes in one launch; block b handles matrix b
struct PrepPtrs { const float* W[13]; };
__global__ void prep_all(PrepPtrs P, f16* __restrict__ out) {
  const int Nw[13]   = {64,64,64,64,64,64,64,64,64,64,64,64,7};
  const int Kd[13]   = {32,64,96,96,64,192,64,128,64,192,64,128,64};
  const int ks[13]   = {0,0,0,5,0,0,0,0,0,0,0,0,0};
  const int kd[13]   = {0,0,0,32,0,0,0,0,0,0,0,0,0};
  const int klen[13] = {14,64,5,64,64,192,64,128,64,192,64,128,64};
  const int nc[13]   = {64,64,64,64,64,64,64,64,64,64,64,64,7};
  const int ofs[13]  = {0,2048,6144,6144,12288,16384,28672,32768,40960,45056,57344,61440,69632};
  const int m = blockIdx.x;
  const float* W = P.W[m];
  const int tot = klen[m] * nc[m];
  for (int idx = threadIdx.x; idx < tot; idx += 256) {
    int kk = idx / nc[m], n = idx % nc[m];
    out[ofs[m] + n * Kd[m] + kd[m] + kk] = (f16)W[(ks[m] + kk) * Nw[m] + n];
  }
}

// ---------------- edge MLP (R13 + fp8 src-gather) ----------------
// STAGE: 0=encoder (A from packed Aenc, write el, agg += el)
//        1=processor (A=[fp8 xq[src]|xh[dst]|el], el += ed in place, agg += ed)
//        2=decoder   (A same as proc, NO el write, agg += ed)
template <int STAGE, int KT1>
__global__ __launch_bounds__(256, 3)
void edge_mlp_kernel(const f16* __restrict__ Aenc,
                     const f16* __restrict__ xh,
                     const unsigned char* __restrict__ xq,
                     const f16* elr, f16* elw,
                     const int* __restrict__ psrc,
                     const int* __restrict__ pdst,
                     const f16* __restrict__ B1,
                     const f16* __restrict__ B2,
                     const float* __restrict__ b1,
                     const float* __restrict__ b2,
                     float* __restrict__ agg) {
  constexpr int K1 = KT1 * 32;
  constexpr int NF1 = KT1 * 4;              // L1 fragment count
  constexpr int NA = (STAGE == 0) ? 1 : 4;  // f16 A fragments (dst + el)
  __shared__ __align__(16) f16 h1s[4][16][72];    // 9216 B
  __shared__ __align__(16) f16 B1s[NF1 * 64 * 8]; // KT1=6: 24576 B
  __shared__ __align__(16) f16 B2s[8 * 64 * 8];   // 8192 B  (total 41984 -> 3 blk/CU)

  const int wave = threadIdx.x >> 6;
  const int lane = threadIdx.x & 63;
  const int l15 = lane & 15, lg = lane >> 4;
  const int NG = NE / 16;

  // XCD-partitioned mapping: 8 partitions of NG/8 contiguous groups
  const int xcd = blockIdx.x & 7;
  const int wlocal = (blockIdx.x >> 3) * 4 + wave;
  const int WPP = (gridDim.x >> 3) * 4;
  const int NGP = NG >> 3;
  const int gBase = xcd * NGP;
  const int gEnd = gBase + NGP;

  // ---- stage weight fragments into LDS (fragment-major, conflict-free reads) ----
  for (int f = wave; f < NF1; f += 4) {
    const int kk = f >> 2, nt = f & 3;
    *(f16x8*)&B1s[(f * 64 + lane) * 8] =
        *(const f16x8*)(B1 + (nt * 16 + l15) * K1 + kk * 32 + lg * 8);
  }
  for (int f = wave; f < 8; f += 4) {
    const int kk = f >> 2, nt = f & 3;
    *(f16x8*)&B2s[(f * 64 + lane) * 8] =
        *(const f16x8*)(B2 + (nt * 16 + l15) * 64 + kk * 32 + lg * 8);
  }
  float bias1[4], bias2[4];
#pragma unroll
  for (int nt = 0; nt < 4; ++nt) { bias1[nt] = b1[nt * 16 + l15]; bias2[nt] = b2[nt * 16 + l15]; }
  __syncthreads();

  // ---- A loaders: src from fp8 mirror (uint2 x2), dst+el from f16 ----
  auto loadA = [&](int g, int s, int d, f16x8* a, uint2& q0, uint2& q1) {
    const int erA = g * 16 + l15;
    if (STAGE == 0) {
      a[0] = fzero8();
      if (lg < 2) a[0] = *(const f16x8*)(Aenc + (size_t)erA * 16 + lg * 8);
    } else {
      q0 = *(const uint2*)(xq + (size_t)s * 64 + lg * 8);
      q1 = *(const uint2*)(xq + (size_t)s * 64 + 32 + lg * 8);
      a[0] = *(const f16x8*)(xh + (size_t)d * 64 + lg * 8);
      a[1] = *(const f16x8*)(xh + (size_t)d * 64 + 32 + lg * 8);
      a[2] = *(const f16x8*)(elr + (size_t)erA * 64 + lg * 8);
      a[3] = *(const f16x8*)(elr + (size_t)erA * 64 + 32 + lg * 8);
    }
  };

  // ---- software pipeline: idx 2-deep, A-frags 1-deep (R7-proven) ----
  const int g1 = gBase + wlocal;
  int sA = 0, dA = 0, sB = 0, dB = 0;
  dA = pdst[g1 * 16 + l15];
  if (STAGE != 0) sA = psrc[g1 * 16 + l15];
  f16x8 aCur[NA], aNxt[NA];
  uint2 qC0, qC1, qN0, qN1;
  loadA(g1, sA, dA, aCur, qC0, qC1);
  {
    const int g2 = g1 + WPP;
    if (g2 < gEnd) {
      dB = pdst[g2 * 16 + l15];
      if (STAGE != 0) sB = psrc[g2 * 16 + l15];
    }
  }

  for (int g = g1; g < gEnd; g += WPP) {
    const int gN = g + WPP;
    if (gN < gEnd) loadA(gN, sB, dB, aNxt, qN0, qN1);   // prefetch next group's A
    int sC = 0, dC = 0;
    const int g3 = g + 2 * WPP;
    if (g3 < gEnd) {
      dC = pdst[g3 * 16 + l15];
      if (STAGE != 0) sC = psrc[g3 * 16 + l15];
    }

    // ---- layer 1: MFMA with LDS B-frags ----
    f32x4 acc[4];
#pragma unroll
    for (int nt = 0; nt < 4; ++nt) { acc[nt][0] = 0.f; acc[nt][1] = 0.f; acc[nt][2] = 0.f; acc[nt][3] = 0.f; }
#pragma unroll
    for (int kk = 0; kk < KT1; ++kk) {
      f16x8 a;
      if (STAGE == 0) {
        a = aCur[0];
      } else {
        if (kk == 0)      a = dec8(qC0);
        else if (kk == 1) a = dec8(qC1);
        else              a = aCur[kk - 2];
      }
#pragma unroll
      for (int nt = 0; nt < 4; ++nt) {
        const f16x8 b = *(const f16x8*)&B1s[((kk * 4 + nt) * 64 + lane) * 8];
        acc[nt] = mfma16(a, b, acc[nt]);
      }
    }
    // bias + relu, stage h1 to LDS (C-layout -> A-layout); per-wave slice
#pragma unroll
    for (int nt = 0; nt < 4; ++nt)
#pragma unroll
      for (int r = 0; r < 4; ++r) {
        float h = fmaxf(acc[nt][r] + bias1[nt], 0.f);
        h1s[wave][lg * 4 + r][nt * 16 + l15] = (f16)h;
      }

    // ---- layer 2 ----
    f32x4 out[4];
#pragma unroll
    for (int nt = 0; nt < 4; ++nt) { out[nt][0] = 0.f; out[nt][1] = 0.f; out[nt][2] = 0.f; out[nt][3] = 0.f; }
#pragma unroll
    for (int kk = 0; kk < 2; ++kk) {
      const f16x8 hf = *(const f16x8*)&h1s[wave][l15][kk * 32 + lg * 8];
#pragma unroll
      for (int nt = 0; nt < 4; ++nt) {
        const f16x8 b = *(const f16x8*)&B2s[((kk * 4 + nt) * 64 + lane) * 8];
        out[nt] = mfma16(hf, b, out[nt]);
      }
    }

    // stage ed (bias added) back to LDS rows
#pragma unroll
    for (int nt = 0; nt < 4; ++nt)
#pragma unroll
      for (int r = 0; r < 4; ++r)
        h1s[wave][lg * 4 + r][nt * 16 + l15] = (f16)(out[nt][r] + bias2[nt]);

    // global el write (encoder: fresh; proc: in-place residual; decoder: none)
    const int erA = g * 16 + l15;
    if (STAGE != 2) {
      f16x8 v0 = *(const f16x8*)&h1s[wave][l15][lg * 8];
      f16x8 v1 = *(const f16x8*)&h1s[wave][l15][32 + lg * 8];
      f16* p0 = elw + (size_t)erA * 64 + lg * 8;
      if (STAGE == 1) {
        f16x8 n0, n1;
#pragma unroll
        for (int j = 0; j < 8; ++j) {
          n0[j] = (f16)((float)aCur[2][j] + (float)v0[j]);
          n1[j] = (f16)((float)aCur[3][j] + (float)v1[j]);
        }
        *(f16x8*)p0 = n0;
        *(f16x8*)(p0 + 32) = n1;
      } else {
        *(f16x8*)p0 = v0;
        *(f16x8*)(p0 + 32) = v1;
      }
    }

    // fused segmented reduction: lane = column, walk 16 sorted rows,
    // one coalesced 64-lane atomicAdd per dst segment (dst wave-uniform).
    {
      float racc = 0.f;
      int dprev = __shfl(dA, 0);
#pragma unroll
      for (int row = 0; row < 16; ++row) {
        const int dn = __shfl(dA, row);
        const float v = (float)h1s[wave][row][lane];
        if (dn != dprev) {
          atomicAdd(agg + (size_t)dprev * 64 + lane, racc);
          racc = 0.f;
          dprev = dn;
        }
        racc += v;
      }
      atomicAdd(agg + (size_t)dprev * 64 + lane, racc);
    }

    // rotate pipeline
#pragma unroll
    for (int i = 0; i < NA; ++i) aCur[i] = aNxt[i];
    qC0 = qN0; qC1 = qN1;
    sA = sB; dA = dB; sB = sC; dB = dC;
  }
}

// ---------------- node MLP (LDS-staged weights, fused mean-finish) ----------------
// STAGE: 0=encoder (A=[x_raw(5,pad32)|agg*inv], out: xl=v, xh=f16(v))
//        1=processor (A=[xh|agg*inv], xl += v, xh mirror)
//        2=decoder   (A=[xh|agg*inv], write d_out[N][7])
template <int STAGE, int KT1, int NT2, int OUTW>
__global__ __launch_bounds__(256, 4)
void node_mlp_kernel(const float* __restrict__ xraw,
                     const f16* xh,
                     const float* __restrict__ agg,
                     const float* __restrict__ inv,
                     const f16* __restrict__ B1,
                     const f16* __restrict__ B2,
                     const float* __restrict__ b1,
                     const float* __restrict__ b2,
                     float* __restrict__ xl,
                     f16* xho,
                     float* __restrict__ outp) {
  constexpr int K1 = KT1 * 32;
  constexpr int NF1 = KT1 * 4;
  constexpr int NF2 = 2 * NT2;
  __shared__ __align__(16) f16 h1s[4][16][72];
  __shared__ __align__(16) f16 B1s[NF1 * 64 * 8];
  __shared__ __align__(16) f16 B2s[NF2 * 64 * 8];
  const int wave = threadIdx.x >> 6;
  const int lane = threadIdx.x & 63;
  const int l15 = lane & 15, lg = lane >> 4;
  const int nwaves = gridDim.x * 4;
  const int wid = blockIdx.x * 4 + wave;
  const int NG = NN / 16;

  for (int f = wave; f < NF1; f += 4) {
    const int kk = f >> 2, nt = f & 3;
    *(f16x8*)&B1s[(f * 64 + lane) * 8] =
        *(const f16x8*)(B1 + (nt * 16 + l15) * K1 + kk * 32 + lg * 8);
  }
  for (int f = wave; f < NF2; f += 4) {
    const int kk = f / NT2, nt = f % NT2;
    *(f16x8*)&B2s[(f * 64 + lane) * 8] =
        *(const f16x8*)(B2 + (nt * 16 + l15) * 64 + kk * 32 + lg * 8);
  }
  float bias1[4], bias2[NT2];
#pragma unroll
  for (int nt = 0; nt < 4; ++nt) bias1[nt] = b1[nt * 16 + l15];
#pragma unroll
  for (int nt = 0; nt < NT2; ++nt) bias2[nt] = (nt * 16 + l15 < OUTW) ? b2[nt * 16 + l15] : 0.f;
  __syncthreads();

  for (int g = wid; g < NG; g += nwaves) {
    const int n0 = g * 16;
    const int rA = n0 + l15;
    const float iv = inv[rA];

    f32x4 acc[4];
#pragma unroll
    for (int nt = 0; nt < 4; ++nt) { acc[nt][0] = 0.f; acc[nt][1] = 0.f; acc[nt][2] = 0.f; acc[nt][3] = 0.f; }

#pragma unroll
    for (int kk = 0; kk < KT1; ++kk) {
      f16x8 a;
      if (STAGE == 0 && kk == 0) {
        a = fzero8();
        if (lg == 0) {
#pragma unroll
          for (int j = 0; j < 5; ++j) a[j] = (f16)xraw[(size_t)rA * 5 + j];
        }
      } else if (STAGE != 0 && kk < 2) {
        a = *(const f16x8*)(xh + (size_t)rA * 64 + kk * 32 + lg * 8);
      } else {
        const int ko = (STAGE == 0) ? (kk - 1) : (kk - 2);
        const float* ap = agg + (size_t)rA * 64 + ko * 32 + lg * 8;
        f32x4 a0 = *(const f32x4*)ap;
        f32x4 a1 = *(const f32x4*)(ap + 4);
#pragma unroll
        for (int j = 0; j < 4; ++j) { a[j] = (f16)(a0[j] * iv); a[4 + j] = (f16)(a1[j] * iv); }
      }
#pragma unroll
      for (int nt = 0; nt < 4; ++nt) {
        const f16x8 b = *(const f16x8*)&B1s[((kk * 4 + nt) * 64 + lane) * 8];
        acc[nt] = mfma16(a, b, acc[nt]);
      }
    }
#pragma unroll
    for (int nt = 0; nt < 4; ++nt)
#pragma unroll
      for (int r = 0; r < 4; ++r) {
        float h = fmaxf(acc[nt][r] + bias1[nt], 0.f);
        h1s[wave][lg * 4 + r][nt * 16 + l15] = (f16)h;
      }

    f32x4 out[NT2];
#pragma unroll
    for (int nt = 0; nt < NT2; ++nt) { out[nt][0] = 0.f; out[nt][1] = 0.f; out[nt][2] = 0.f; out[nt][3] = 0.f; }
#pragma unroll
    for (int kk = 0; kk < 2; ++kk) {
      const f16x8 hf = *(const f16x8*)&h1s[wave][l15][kk * 32 + lg * 8];
#pragma unroll
      for (int nt = 0; nt < NT2; ++nt) {
        const f16x8 b = *(const f16x8*)&B2s[((kk * NT2 + nt) * 64 + lane) * 8];
        out[nt] = mfma16(hf, b, out[nt]);
      }
    }
#pragma unroll
    for (int r = 0; r < 4; ++r) {
      const int row = n0 + lg * 4 + r;
#pragma unroll
      for (int nt = 0; nt < NT2; ++nt) {
        const int col = nt * 16 + l15;
        float v = out[nt][r] + bias2[nt];
        if (STAGE == 0) {
          xl[(size_t)row * 64 + col] = v;
          xho[(size_t)row * 64 + col] = (f16)v;
        } else if (STAGE == 1) {
          float nv = xl[(size_t)row * 64 + col] + v;
          xl[(size_t)row * 64 + col] = nv;
          xho[(size_t)row * 64 + col] = (f16)nv;
        } else {
          if (col < OUTW) outp[(size_t)row * OUTW + col] = v;
        }
      }
    }
  }
}

// ---------------- launch ----------------

extern "C" void kernel_launch(void* const* d_in, const int* in_sizes, int n_in,
                              void* d_out, int out_size, void* d_ws, size_t ws_size,
                              hipStream_t stream) {
  const float* x  = (const float*)d_in[0];
  const int* ei   = (const int*)d_in[1];
  const float* ea = (const float*)d_in[2];
  const float* enc_e_b1 = (const float*)d_in[4];
  const float* enc_e_b2 = (const float*)d_in[6];
  const float* enc_n_b1 = (const float*)d_in[8];
  const float* enc_n_b2 = (const float*)d_in[10];
  const float* proc_e_b1 = (const float*)d_in[12];
  const float* proc_e_b2 = (const float*)d_in[14];
  const float* proc_n_b1 = (const float*)d_in[16];
  const float* proc_n_b2 = (const float*)d_in[18];
  const float* dec_e_b1 = (const float*)d_in[20];
  const float* dec_e_b2 = (const float*)d_in[22];
  const float* dec_n_b1 = (const float*)d_in[24];
  const float* dec_n_b2 = (const float*)d_in[26];

  const int* src = ei;
  const int* dst = ei + NE;

  // workspace layout (~170 MB total; R2 proved >= 263 MB available)
  char* p = (char*)d_ws;
  f16* el    = (f16*)p;   p += (size_t)NE * 64 * 2;   // 102.4 MB
  f16* Aenc  = (f16*)p;   p += (size_t)NE * 16 * 2;   // 25.6 MB
  float* xl  = (float*)p; p += (size_t)NN * 64 * 4;   // 12.8 MB
  f16* xh    = (f16*)p;   p += (size_t)NN * 64 * 2;   // 6.4 MB
  unsigned char* xq = (unsigned char*)p; p += (size_t)NN * 64;  // 3.2 MB fp8 mirror
  float* agg = (float*)p; p += (size_t)NN * 64 * 4;   // 12.8 MB f32 atomic accumulator
  int* cnt   = (int*)p;   p += (size_t)NN * 4;
  int* off   = (int*)p;   p += (size_t)(NN + 1) * 4;
  int* cur   = (int*)p;   p += (size_t)NN * 4;
  float* inv = (float*)p; p += (size_t)NN * 4;
  int* psrc  = (int*)p;   p += (size_t)NE * 4;
  int* pdst  = (int*)p;   p += (size_t)NE * 4;
  f16* wb    = (f16*)p;   p += 70656 * 2;
  f16* W1T_ence = wb + 0;
  f16* W2T_ence = wb + 2048;
  f16* W1T_encn = wb + 6144;
  f16* W2T_encn = wb + 12288;
  f16* W1T_proce = wb + 16384;
  f16* W2T_proce = wb + 28672;
  f16* W1T_procn = wb + 32768;
  f16* W2T_procn = wb + 40960;
  f16* W1T_dece = wb + 45056;
  f16* W2T_dece = wb + 57344;
  f16* W1T_decn = wb + 61440;
  f16* W2T_decn = wb + 69632;

  hipMemsetAsync(cnt, 0, (size_t)NN * 4, stream);
  hipMemsetAsync(wb, 0, 70656 * 2, stream);

  count_kernel<<<(NE + 255) / 256, 256, 0, stream>>>(dst, cnt);
  scan_kernel<<<1, 1024, 0, stream>>>(cnt, off, cur, inv);
  scatter_pack<<<(NE + 255) / 256, 256, 0, stream>>>(x, ea, src, dst, cur, psrc, pdst, Aenc);

  PrepPtrs P;
  P.W[0]  = (const float*)d_in[3];   // enc_e_w1
  P.W[1]  = (const float*)d_in[5];   // enc_e_w2
  P.W[2]  = (const float*)d_in[7];   // enc_n_w1 (raw part)
  P.W[3]  = (const float*)d_in[7];   // enc_n_w1 (agg part)
  P.W[4]  = (const float*)d_in[9];   // enc_n_w2
  P.W[5]  = (const float*)d_in[11];  // proc_e_w1
  P.W[6]  = (const float*)d_in[13];  // proc_e_w2
  P.W[7]  = (const float*)d_in[15];  // proc_n_w1
  P.W[8]  = (const float*)d_in[17];  // proc_n_w2
  P.W[9]  = (const float*)d_in[19];  // dec_e_w1
  P.W[10] = (const float*)d_in[21];  // dec_e_w2
  P.W[11] = (const float*)d_in[23];  // dec_n_w1
  P.W[12] = (const float*)d_in[25];  // dec_n_w2
  prep_all<<<13, 256, 0, stream>>>(P, wb);

  // 768 blocks = 96 per XCD = exactly 3 resident blocks/CU; XCD-partitioned mapping
  const int EDGE_BLK = 768;
  const int XQ_BLK = (NN * 8 + 255) / 256;
  const size_t AGG_BYTES = (size_t)NN * 64 * 4;

  // ---- encoder ----
  hipMemsetAsync(agg, 0, AGG_BYTES, stream);
  edge_mlp_kernel<0, 1><<<EDGE_BLK, 256, 0, stream>>>(Aenc, xh, xq, el, el, psrc, pdst,
                                                      W1T_ence, W2T_ence, enc_e_b1, enc_e_b2, agg);
  node_mlp_kernel<0, 3, 4, 64><<<256, 256, 0, stream>>>(x, xh, agg, inv, W1T_encn, W2T_encn,
                                                        enc_n_b1, enc_n_b2, xl, xh, (float*)d_out);
  xq_kernel<<<XQ_BLK, 256, 0, stream>>>(xh, xq);
  // ---- 2 processor rounds (shared weights, residuals) ----
  for (int r = 0; r < 2; ++r) {
    hipMemsetAsync(agg, 0, AGG_BYTES, stream);
    edge_mlp_kernel<1, 6><<<EDGE_BLK, 256, 0, stream>>>(Aenc, xh, xq, el, el, psrc, pdst,
                                                        W1T_proce, W2T_proce, proc_e_b1, proc_e_b2, agg);
    node_mlp_kernel<1, 4, 4, 64><<<256, 256, 0, stream>>>(x, xh, agg, inv, W1T_procn, W2T_procn,
                                                          proc_n_b1, proc_n_b2, xl, xh, (float*)d_out);
    xq_kernel<<<XQ_BLK, 256, 0, stream>>>(xh, xq);
  }
  // ---- decoder (no el write; agg of ed only) ----
  hipMemsetAsync(agg, 0, AGG_BYTES, stream);
  edge_mlp_kernel<2, 6><<<EDGE_BLK, 256, 0, stream>>>(Aenc, xh, xq, el, el, psrc, pdst,
                                                      W1T_dece, W2T_dece, dec_e_b1, dec_e_b2, agg);
  node_mlp_kernel<2, 4, 1, 7><<<256, 256, 0, stream>>>(x, xh, agg, inv, W1T_decn, W2T_decn,
                                                       dec_n_b1, dec_n_b2, xl, xh, (float*)d_out);
}

// Round 16
// 666.403 us; speedup vs baseline: 1.7155x; 1.0377x over previous
//
#include <hip/hip_runtime.h>

#define NN 50000
#define NE 800000

typedef _Float16 f16;
typedef _Float16 f16x8 __attribute__((ext_vector_type(8)));
typedef float f32x4 __attribute__((ext_vector_type(4)));
typedef float f32x2 __attribute__((ext_vector_type(2)));

__device__ __forceinline__ f16x8 fzero8() {
  f16x8 v;
#pragma unroll
  for (int i = 0; i < 8; ++i) v[i] = (f16)0.f;
  return v;
}

__device__ __forceinline__ f32x4 mfma16(f16x8 a, f16x8 b, f32x4 c) {
  return __builtin_amdgcn_mfma_f32_16x16x32_f16(a, b, c, 0, 0, 0);
}

// decode 8 packed fp8(e4m3, native gfx950) -> f16x8 via HW cvt + scalar f32->f16
__device__ __forceinline__ f16x8 dec8(uint2 q) {
  f32x2 f0 = __builtin_amdgcn_cvt_pk_f32_fp8(q.x, false);
  f32x2 f1 = __builtin_amdgcn_cvt_pk_f32_fp8(q.x, true);
  f32x2 f2 = __builtin_amdgcn_cvt_pk_f32_fp8(q.y, false);
  f32x2 f3 = __builtin_amdgcn_cvt_pk_f32_fp8(q.y, true);
  f16x8 r;
  r[0] = (f16)f0[0]; r[1] = (f16)f0[1];
  r[2] = (f16)f1[0]; r[3] = (f16)f1[1];
  r[4] = (f16)f2[0]; r[5] = (f16)f2[1];
  r[6] = (f16)f3[0]; r[7] = (f16)f3[1];
  return r;
}

// encode f16x8 -> 8 packed fp8(e4m3)
__device__ __forceinline__ uint2 enc8(f16x8 v) {
  unsigned lo = 0, hi = 0;
  lo = __builtin_amdgcn_cvt_pk_fp8_f32((float)v[0], (float)v[1], lo, false);
  lo = __builtin_amdgcn_cvt_pk_fp8_f32((float)v[2], (float)v[3], lo, true);
  hi = __builtin_amdgcn_cvt_pk_fp8_f32((float)v[4], (float)v[5], hi, false);
  hi = __builtin_amdgcn_cvt_pk_fp8_f32((float)v[6], (float)v[7], hi, true);
  uint2 q; q.x = lo; q.y = hi;
  return q;
}

// ---------------- prep kernels ----------------

__global__ void count_kernel(const int* __restrict__ dst, int* __restrict__ cnt) {
  int e = blockIdx.x * 256 + threadIdx.x;
  if (e < NE) atomicAdd(&cnt[dst[e]], 1);
}

// single-block exclusive scan over cnt -> off/cur, plus inv = 1/max(cnt,1)
__global__ void scan_kernel(const int* __restrict__ cnt, int* __restrict__ off,
                            int* __restrict__ cur, float* __restrict__ inv) {
  __shared__ int part[1024];
  const int t = threadIdx.x;
  const int CH = (NN + 1023) / 1024;
  const int i0 = t * CH, i1 = (i0 + CH < NN) ? i0 + CH : NN;
  int s = 0;
  for (int i = i0; i < i1; ++i) s += cnt[i];
  part[t] = s;
  __syncthreads();
  for (int d = 1; d < 1024; d <<= 1) {
    int v = (t >= d) ? part[t - d] : 0;
    __syncthreads();
    part[t] += v;
    __syncthreads();
  }
  int base = (t > 0) ? part[t - 1] : 0;
  for (int i = i0; i < i1; ++i) {
    off[i] = base;
    cur[i] = base;
    inv[i] = 1.0f / fmaxf((float)cnt[i], 1.0f);
    base += cnt[i];
  }
  if (t == 1023) off[NN] = NE;
}

// scatter edges into dst-sorted order; also build packed encoder rows
__global__ void scatter_pack(const float* __restrict__ x, const float* __restrict__ ea,
                             const int* __restrict__ src, const int* __restrict__ dst,
                             int* __restrict__ cur, int* __restrict__ psrc,
                             int* __restrict__ pdst, f16* __restrict__ A) {
  int e = blockIdx.x * 256 + threadIdx.x;
  if (e >= NE) return;
  int s = src[e], d = dst[e];
  int pos = atomicAdd(&cur[d], 1);
  psrc[pos] = s;
  pdst[pos] = d;
  f16 row[16];
#pragma unroll
  for (int i = 0; i < 5; ++i) { row[i] = (f16)x[s * 5 + i]; row[5 + i] = (f16)x[d * 5 + i]; }
#pragma unroll
  for (int i = 0; i < 4; ++i) row[10 + i] = (f16)ea[e * 4 + i];
  row[14] = (f16)0.f; row[15] = (f16)0.f;
  *(f16x8*)(A + (size_t)pos * 16) = *(f16x8*)row;
  *(f16x8*)(A + (size_t)pos * 16 + 8) = *(f16x8*)(row + 8);
}

// f16 xh -> fp8 gather mirror xq (3.2 MB, fits a 4MB XCD L2)
__global__ void xq_kernel(const f16* __restrict__ xh, unsigned char* __restrict__ xq) {
  int i = blockIdx.x * 256 + threadIdx.x;  // over NN*8 rows of 8 elems
  if (i >= NN * 8) return;
  f16x8 v = *(const f16x8*)(xh + (size_t)i * 8);
  uint2 q = enc8(v);
  *(uint2*)(xq + (size_t)i * 8) = q;
}

// all 13 weight transposes in one launch; block b handles matrix b
struct PrepPtrs { const float* W[13]; };
__global__ void prep_all(PrepPtrs P, f16* __restrict__ out) {
  const int Nw[13]   = {64,64,64,64,64,64,64,64,64,64,64,64,7};
  const int Kd[13]   = {32,64,96,96,64,192,64,128,64,192,64,128,64};
  const int ks[13]   = {0,0,0,5,0,0,0,0,0,0,0,0,0};
  const int kd[13]   = {0,0,0,32,0,0,0,0,0,0,0,0,0};
  const int klen[13] = {14,64,5,64,64,192,64,128,64,192,64,128,64};
  const int nc[13]   = {64,64,64,64,64,64,64,64,64,64,64,64,7};
  const int ofs[13]  = {0,2048,6144,6144,12288,16384,28672,32768,40960,45056,57344,61440,69632};
  const int m = blockIdx.x;
  const float* W = P.W[m];
  const int tot = klen[m] * nc[m];
  for (int idx = threadIdx.x; idx < tot; idx += 256) {
    int kk = idx / nc[m], n = idx % nc[m];
    out[ofs[m] + n * Kd[m] + kd[m] + kk] = (f16)W[(ks[m] + kk) * Nw[m] + n];
  }
}

// ---------------- edge MLP (R13 + fp8 src-gather + fp8 el stream) ----------------
// STAGE: 0=encoder (A from packed Aenc, write el fp8, agg += el)
//        1=processor (A=[fp8 xq[src]|xh[dst]|fp8 el], el += ed in place, agg += ed)
//        2=decoder   (A same as proc, NO el write, agg += ed)
template <int STAGE, int KT1>
__global__ __launch_bounds__(256, 3)
void edge_mlp_kernel(const f16* __restrict__ Aenc,
                     const f16* __restrict__ xh,
                     const unsigned char* __restrict__ xq,
                     const unsigned char* elr, unsigned char* elw,
                     const int* __restrict__ psrc,
                     const int* __restrict__ pdst,
                     const f16* __restrict__ B1,
                     const f16* __restrict__ B2,
                     const float* __restrict__ b1,
                     const float* __restrict__ b2,
                     float* __restrict__ agg) {
  constexpr int K1 = KT1 * 32;
  constexpr int NF1 = KT1 * 4;              // L1 fragment count
  constexpr int NA = (STAGE == 0) ? 1 : 2;  // f16 A fragments (dst only)
  __shared__ __align__(16) f16 h1s[4][16][72];    // 9216 B
  __shared__ __align__(16) f16 B1s[NF1 * 64 * 8]; // KT1=6: 24576 B
  __shared__ __align__(16) f16 B2s[8 * 64 * 8];   // 8192 B  (total 41984 -> 3 blk/CU)

  const int wave = threadIdx.x >> 6;
  const int lane = threadIdx.x & 63;
  const int l15 = lane & 15, lg = lane >> 4;
  const int NG = NE / 16;

  // XCD-partitioned mapping: 8 partitions of NG/8 contiguous groups
  const int xcd = blockIdx.x & 7;
  const int wlocal = (blockIdx.x >> 3) * 4 + wave;
  const int WPP = (gridDim.x >> 3) * 4;
  const int NGP = NG >> 3;
  const int gBase = xcd * NGP;
  const int gEnd = gBase + NGP;

  // ---- stage weight fragments into LDS (fragment-major, conflict-free reads) ----
  for (int f = wave; f < NF1; f += 4) {
    const int kk = f >> 2, nt = f & 3;
    *(f16x8*)&B1s[(f * 64 + lane) * 8] =
        *(const f16x8*)(B1 + (nt * 16 + l15) * K1 + kk * 32 + lg * 8);
  }
  for (int f = wave; f < 8; f += 4) {
    const int kk = f >> 2, nt = f & 3;
    *(f16x8*)&B2s[(f * 64 + lane) * 8] =
        *(const f16x8*)(B2 + (nt * 16 + l15) * 64 + kk * 32 + lg * 8);
  }
  float bias1[4], bias2[4];
#pragma unroll
  for (int nt = 0; nt < 4; ++nt) { bias1[nt] = b1[nt * 16 + l15]; bias2[nt] = b2[nt * 16 + l15]; }
  __syncthreads();

  // ---- A loaders: src + el from fp8 (uint2 x2 each), dst from f16 ----
  auto loadA = [&](int g, int s, int d, f16x8* a,
                   uint2& qs0, uint2& qs1, uint2& qe0, uint2& qe1) {
    const int erA = g * 16 + l15;
    if (STAGE == 0) {
      a[0] = fzero8();
      if (lg < 2) a[0] = *(const f16x8*)(Aenc + (size_t)erA * 16 + lg * 8);
    } else {
      qs0 = *(const uint2*)(xq + (size_t)s * 64 + lg * 8);
      qs1 = *(const uint2*)(xq + (size_t)s * 64 + 32 + lg * 8);
      a[0] = *(const f16x8*)(xh + (size_t)d * 64 + lg * 8);
      a[1] = *(const f16x8*)(xh + (size_t)d * 64 + 32 + lg * 8);
      qe0 = *(const uint2*)(elr + (size_t)erA * 64 + lg * 8);
      qe1 = *(const uint2*)(elr + (size_t)erA * 64 + 32 + lg * 8);
    }
  };

  // ---- software pipeline: idx 2-deep, A-frags 1-deep (R7-proven) ----
  const int g1 = gBase + wlocal;
  int sA = 0, dA = 0, sB = 0, dB = 0;
  dA = pdst[g1 * 16 + l15];
  if (STAGE != 0) sA = psrc[g1 * 16 + l15];
  f16x8 aCur[NA], aNxt[NA];
  uint2 qsC0, qsC1, qeC0, qeC1;
  uint2 qsN0, qsN1, qeN0, qeN1;
  loadA(g1, sA, dA, aCur, qsC0, qsC1, qeC0, qeC1);
  {
    const int g2 = g1 + WPP;
    if (g2 < gEnd) {
      dB = pdst[g2 * 16 + l15];
      if (STAGE != 0) sB = psrc[g2 * 16 + l15];
    }
  }

  for (int g = g1; g < gEnd; g += WPP) {
    const int gN = g + WPP;
    if (gN < gEnd) loadA(gN, sB, dB, aNxt, qsN0, qsN1, qeN0, qeN1);
    int sC = 0, dC = 0;
    const int g3 = g + 2 * WPP;
    if (g3 < gEnd) {
      dC = pdst[g3 * 16 + l15];
      if (STAGE != 0) sC = psrc[g3 * 16 + l15];
    }

    // decode el once per group (used by MFMA + residual epilogue)
    f16x8 eC0 = fzero8(), eC1 = fzero8();
    if (STAGE != 0) { eC0 = dec8(qeC0); eC1 = dec8(qeC1); }

    // ---- layer 1: MFMA with LDS B-frags ----
    f32x4 acc[4];
#pragma unroll
    for (int nt = 0; nt < 4; ++nt) { acc[nt][0] = 0.f; acc[nt][1] = 0.f; acc[nt][2] = 0.f; acc[nt][3] = 0.f; }
#pragma unroll
    for (int kk = 0; kk < KT1; ++kk) {
      f16x8 a;
      if (STAGE == 0) {
        a = aCur[0];
      } else {
        if (kk == 0)      a = dec8(qsC0);
        else if (kk == 1) a = dec8(qsC1);
        else if (kk < 4)  a = aCur[kk - 2];
        else              a = (kk == 4) ? eC0 : eC1;
      }
#pragma unroll
      for (int nt = 0; nt < 4; ++nt) {
        const f16x8 b = *(const f16x8*)&B1s[((kk * 4 + nt) * 64 + lane) * 8];
        acc[nt] = mfma16(a, b, acc[nt]);
      }
    }
    // bias + relu, stage h1 to LDS (C-layout -> A-layout); per-wave slice
#pragma unroll
    for (int nt = 0; nt < 4; ++nt)
#pragma unroll
      for (int r = 0; r < 4; ++r) {
        float h = fmaxf(acc[nt][r] + bias1[nt], 0.f);
        h1s[wave][lg * 4 + r][nt * 16 + l15] = (f16)h;
      }

    // ---- layer 2 ----
    f32x4 out[4];
#pragma unroll
    for (int nt = 0; nt < 4; ++nt) { out[nt][0] = 0.f; out[nt][1] = 0.f; out[nt][2] = 0.f; out[nt][3] = 0.f; }
#pragma unroll
    for (int kk = 0; kk < 2; ++kk) {
      const f16x8 hf = *(const f16x8*)&h1s[wave][l15][kk * 32 + lg * 8];
#pragma unroll
      for (int nt = 0; nt < 4; ++nt) {
        const f16x8 b = *(const f16x8*)&B2s[((kk * 4 + nt) * 64 + lane) * 8];
        out[nt] = mfma16(hf, b, out[nt]);
      }
    }

    // stage ed (bias added) back to LDS rows
#pragma unroll
    for (int nt = 0; nt < 4; ++nt)
#pragma unroll
      for (int r = 0; r < 4; ++r)
        h1s[wave][lg * 4 + r][nt * 16 + l15] = (f16)(out[nt][r] + bias2[nt]);

    // global el write (fp8; encoder: fresh; proc: in-place residual; decoder: none)
    const int erA = g * 16 + l15;
    if (STAGE != 2) {
      f16x8 v0 = *(const f16x8*)&h1s[wave][l15][lg * 8];
      f16x8 v1 = *(const f16x8*)&h1s[wave][l15][32 + lg * 8];
      unsigned char* p0 = elw + (size_t)erA * 64 + lg * 8;
      if (STAGE == 1) {
        f16x8 n0, n1;
#pragma unroll
        for (int j = 0; j < 8; ++j) {
          n0[j] = (f16)((float)eC0[j] + (float)v0[j]);
          n1[j] = (f16)((float)eC1[j] + (float)v1[j]);
        }
        *(uint2*)p0 = enc8(n0);
        *(uint2*)(p0 + 32) = enc8(n1);
      } else {
        *(uint2*)p0 = enc8(v0);
        *(uint2*)(p0 + 32) = enc8(v1);
      }
    }

    // fused segmented reduction: lane = column, walk 16 sorted rows,
    // one coalesced 64-lane atomicAdd per dst segment (dst wave-uniform).
    {
      float racc = 0.f;
      int dprev = __shfl(dA, 0);
#pragma unroll
      for (int row = 0; row < 16; ++row) {
        const int dn = __shfl(dA, row);
        const float v = (float)h1s[wave][row][lane];
        if (dn != dprev) {
          atomicAdd(agg + (size_t)dprev * 64 + lane, racc);
          racc = 0.f;
          dprev = dn;
        }
        racc += v;
      }
      atomicAdd(agg + (size_t)dprev * 64 + lane, racc);
    }

    // rotate pipeline
#pragma unroll
    for (int i = 0; i < NA; ++i) aCur[i] = aNxt[i];
    qsC0 = qsN0; qsC1 = qsN1; qeC0 = qeN0; qeC1 = qeN1;
    sA = sB; dA = dB; sB = sC; dB = dC;
  }
}

// ---------------- node MLP (LDS-staged weights, fused mean-finish) ----------------
// STAGE: 0=encoder (A=[x_raw(5,pad32)|agg*inv], out: xl=v, xh=f16(v))
//        1=processor (A=[xh|agg*inv], xl += v, xh mirror)
//        2=decoder   (A=[xh|agg*inv], write d_out[N][7])
template <int STAGE, int KT1, int NT2, int OUTW>
__global__ __launch_bounds__(256, 4)
void node_mlp_kernel(const float* __restrict__ xraw,
                     const f16* xh,
                     const float* __restrict__ agg,
                     const float* __restrict__ inv,
                     const f16* __restrict__ B1,
                     const f16* __restrict__ B2,
                     const float* __restrict__ b1,
                     const float* __restrict__ b2,
                     float* __restrict__ xl,
                     f16* xho,
                     float* __restrict__ outp) {
  constexpr int K1 = KT1 * 32;
  constexpr int NF1 = KT1 * 4;
  constexpr int NF2 = 2 * NT2;
  __shared__ __align__(16) f16 h1s[4][16][72];
  __shared__ __align__(16) f16 B1s[NF1 * 64 * 8];
  __shared__ __align__(16) f16 B2s[NF2 * 64 * 8];
  const int wave = threadIdx.x >> 6;
  const int lane = threadIdx.x & 63;
  const int l15 = lane & 15, lg = lane >> 4;
  const int nwaves = gridDim.x * 4;
  const int wid = blockIdx.x * 4 + wave;
  const int NG = NN / 16;

  for (int f = wave; f < NF1; f += 4) {
    const int kk = f >> 2, nt = f & 3;
    *(f16x8*)&B1s[(f * 64 + lane) * 8] =
        *(const f16x8*)(B1 + (nt * 16 + l15) * K1 + kk * 32 + lg * 8);
  }
  for (int f = wave; f < NF2; f += 4) {
    const int kk = f / NT2, nt = f % NT2;
    *(f16x8*)&B2s[(f * 64 + lane) * 8] =
        *(const f16x8*)(B2 + (nt * 16 + l15) * 64 + kk * 32 + lg * 8);
  }
  float bias1[4], bias2[NT2];
#pragma unroll
  for (int nt = 0; nt < 4; ++nt) bias1[nt] = b1[nt * 16 + l15];
#pragma unroll
  for (int nt = 0; nt < NT2; ++nt) bias2[nt] = (nt * 16 + l15 < OUTW) ? b2[nt * 16 + l15] : 0.f;
  __syncthreads();

  for (int g = wid; g < NG; g += nwaves) {
    const int n0 = g * 16;
    const int rA = n0 + l15;
    const float iv = inv[rA];

    f32x4 acc[4];
#pragma unroll
    for (int nt = 0; nt < 4; ++nt) { acc[nt][0] = 0.f; acc[nt][1] = 0.f; acc[nt][2] = 0.f; acc[nt][3] = 0.f; }

#pragma unroll
    for (int kk = 0; kk < KT1; ++kk) {
      f16x8 a;
      if (STAGE == 0 && kk == 0) {
        a = fzero8();
        if (lg == 0) {
#pragma unroll
          for (int j = 0; j < 5; ++j) a[j] = (f16)xraw[(size_t)rA * 5 + j];
        }
      } else if (STAGE != 0 && kk < 2) {
        a = *(const f16x8*)(xh + (size_t)rA * 64 + kk * 32 + lg * 8);
      } else {
        const int ko = (STAGE == 0) ? (kk - 1) : (kk - 2);
        const float* ap = agg + (size_t)rA * 64 + ko * 32 + lg * 8;
        f32x4 a0 = *(const f32x4*)ap;
        f32x4 a1 = *(const f32x4*)(ap + 4);
#pragma unroll
        for (int j = 0; j < 4; ++j) { a[j] = (f16)(a0[j] * iv); a[4 + j] = (f16)(a1[j] * iv); }
      }
#pragma unroll
      for (int nt = 0; nt < 4; ++nt) {
        const f16x8 b = *(const f16x8*)&B1s[((kk * 4 + nt) * 64 + lane) * 8];
        acc[nt] = mfma16(a, b, acc[nt]);
      }
    }
#pragma unroll
    for (int nt = 0; nt < 4; ++nt)
#pragma unroll
      for (int r = 0; r < 4; ++r) {
        float h = fmaxf(acc[nt][r] + bias1[nt], 0.f);
        h1s[wave][lg * 4 + r][nt * 16 + l15] = (f16)h;
      }

    f32x4 out[NT2];
#pragma unroll
    for (int nt = 0; nt < NT2; ++nt) { out[nt][0] = 0.f; out[nt][1] = 0.f; out[nt][2] = 0.f; out[nt][3] = 0.f; }
#pragma unroll
    for (int kk = 0; kk < 2; ++kk) {
      const f16x8 hf = *(const f16x8*)&h1s[wave][l15][kk * 32 + lg * 8];
#pragma unroll
      for (int nt = 0; nt < NT2; ++nt) {
        const f16x8 b = *(const f16x8*)&B2s[((kk * NT2 + nt) * 64 + lane) * 8];
        out[nt] = mfma16(hf, b, out[nt]);
      }
    }
#pragma unroll
    for (int r = 0; r < 4; ++r) {
      const int row = n0 + lg * 4 + r;
#pragma unroll
      for (int nt = 0; nt < NT2; ++nt) {
        const int col = nt * 16 + l15;
        float v = out[nt][r] + bias2[nt];
        if (STAGE == 0) {
          xl[(size_t)row * 64 + col] = v;
          xho[(size_t)row * 64 + col] = (f16)v;
        } else if (STAGE == 1) {
          float nv = xl[(size_t)row * 64 + col] + v;
          xl[(size_t)row * 64 + col] = nv;
          xho[(size_t)row * 64 + col] = (f16)nv;
        } else {
          if (col < OUTW) outp[(size_t)row * OUTW + col] = v;
        }
      }
    }
  }
}

// ---------------- launch ----------------

extern "C" void kernel_launch(void* const* d_in, const int* in_sizes, int n_in,
                              void* d_out, int out_size, void* d_ws, size_t ws_size,
                              hipStream_t stream) {
  const float* x  = (const float*)d_in[0];
  const int* ei   = (const int*)d_in[1];
  const float* ea = (const float*)d_in[2];
  const float* enc_e_b1 = (const float*)d_in[4];
  const float* enc_e_b2 = (const float*)d_in[6];
  const float* enc_n_b1 = (const float*)d_in[8];
  const float* enc_n_b2 = (const float*)d_in[10];
  const float* proc_e_b1 = (const float*)d_in[12];
  const float* proc_e_b2 = (const float*)d_in[14];
  const float* proc_n_b1 = (const float*)d_in[16];
  const float* proc_n_b2 = (const float*)d_in[18];
  const float* dec_e_b1 = (const float*)d_in[20];
  const float* dec_e_b2 = (const float*)d_in[22];
  const float* dec_n_b1 = (const float*)d_in[24];
  const float* dec_n_b2 = (const float*)d_in[26];

  const int* src = ei;
  const int* dst = ei + NE;

  // workspace layout (~120 MB total; R2 proved >= 263 MB available)
  char* p = (char*)d_ws;
  unsigned char* el = (unsigned char*)p; p += (size_t)NE * 64;  // 51.2 MB fp8 edge latents
  f16* Aenc  = (f16*)p;   p += (size_t)NE * 16 * 2;   // 25.6 MB
  float* xl  = (float*)p; p += (size_t)NN * 64 * 4;   // 12.8 MB
  f16* xh    = (f16*)p;   p += (size_t)NN * 64 * 2;   // 6.4 MB
  unsigned char* xq = (unsigned char*)p; p += (size_t)NN * 64;  // 3.2 MB fp8 mirror
  float* agg = (float*)p; p += (size_t)NN * 64 * 4;   // 12.8 MB f32 atomic accumulator
  int* cnt   = (int*)p;   p += (size_t)NN * 4;
  int* off   = (int*)p;   p += (size_t)(NN + 1) * 4;
  int* cur   = (int*)p;   p += (size_t)NN * 4;
  float* inv = (float*)p; p += (size_t)NN * 4;
  int* psrc  = (int*)p;   p += (size_t)NE * 4;
  int* pdst  = (int*)p;   p += (size_t)NE * 4;
  f16* wb    = (f16*)p;   p += 70656 * 2;
  f16* W1T_ence = wb + 0;
  f16* W2T_ence = wb + 2048;
  f16* W1T_encn = wb + 6144;
  f16* W2T_encn = wb + 12288;
  f16* W1T_proce = wb + 16384;
  f16* W2T_proce = wb + 28672;
  f16* W1T_procn = wb + 32768;
  f16* W2T_procn = wb + 40960;
  f16* W1T_dece = wb + 45056;
  f16* W2T_dece = wb + 57344;
  f16* W1T_decn = wb + 61440;
  f16* W2T_decn = wb + 69632;

  hipMemsetAsync(cnt, 0, (size_t)NN * 4, stream);
  hipMemsetAsync(wb, 0, 70656 * 2, stream);

  count_kernel<<<(NE + 255) / 256, 256, 0, stream>>>(dst, cnt);
  scan_kernel<<<1, 1024, 0, stream>>>(cnt, off, cur, inv);
  scatter_pack<<<(NE + 255) / 256, 256, 0, stream>>>(x, ea, src, dst, cur, psrc, pdst, Aenc);

  PrepPtrs P;
  P.W[0]  = (const float*)d_in[3];   // enc_e_w1
  P.W[1]  = (const float*)d_in[5];   // enc_e_w2
  P.W[2]  = (const float*)d_in[7];   // enc_n_w1 (raw part)
  P.W[3]  = (const float*)d_in[7];   // enc_n_w1 (agg part)
  P.W[4]  = (const float*)d_in[9];   // enc_n_w2
  P.W[5]  = (const float*)d_in[11];  // proc_e_w1
  P.W[6]  = (const float*)d_in[13];  // proc_e_w2
  P.W[7]  = (const float*)d_in[15];  // proc_n_w1
  P.W[8]  = (const float*)d_in[17];  // proc_n_w2
  P.W[9]  = (const float*)d_in[19];  // dec_e_w1
  P.W[10] = (const float*)d_in[21];  // dec_e_w2
  P.W[11] = (const float*)d_in[23];  // dec_n_w1
  P.W[12] = (const float*)d_in[25];  // dec_n_w2
  prep_all<<<13, 256, 0, stream>>>(P, wb);

  // 768 blocks = 96 per XCD = exactly 3 resident blocks/CU; XCD-partitioned mapping
  const int EDGE_BLK = 768;
  const int XQ_BLK = (NN * 8 + 255) / 256;
  const size_t AGG_BYTES = (size_t)NN * 64 * 4;

  // ---- encoder ----
  hipMemsetAsync(agg, 0, AGG_BYTES, stream);
  edge_mlp_kernel<0, 1><<<EDGE_BLK, 256, 0, stream>>>(Aenc, xh, xq, el, el, psrc, pdst,
                                                      W1T_ence, W2T_ence, enc_e_b1, enc_e_b2, agg);
  node_mlp_kernel<0, 3, 4, 64><<<256, 256, 0, stream>>>(x, xh, agg, inv, W1T_encn, W2T_encn,
                                                        enc_n_b1, enc_n_b2, xl, xh, (float*)d_out);
  xq_kernel<<<XQ_BLK, 256, 0, stream>>>(xh, xq);
  // ---- 2 processor rounds (shared weights, residuals) ----
  for (int r = 0; r < 2; ++r) {
    hipMemsetAsync(agg, 0, AGG_BYTES, stream);
    edge_mlp_kernel<1, 6><<<EDGE_BLK, 256, 0, stream>>>(Aenc, xh, xq, el, el, psrc, pdst,
                                                        W1T_proce, W2T_proce, proc_e_b1, proc_e_b2, agg);
    node_mlp_kernel<1, 4, 4, 64><<<256, 256, 0, stream>>>(x, xh, agg, inv, W1T_procn, W2T_procn,
                                                          proc_n_b1, proc_n_b2, xl, xh, (float*)d_out);
    xq_kernel<<<XQ_BLK, 256, 0, stream>>>(xh, xq);
  }
  // ---- decoder (no el write; agg of ed only) ----
  hipMemsetAsync(agg, 0, AGG_BYTES, stream);
  edge_mlp_kernel<2, 6><<<EDGE_BLK, 256, 0, stream>>>(Aenc, xh, xq, el, el, psrc, pdst,
                                                      W1T_dece, W2T_dece, dec_e_b1, dec_e_b2, agg);
  node_mlp_kernel<2, 4, 1, 7><<<256, 256, 0, stream>>>(x, xh, agg, inv, W1T_decn, W2T_decn,
                                                       dec_n_b1, dec_n_b2, xl, xh, (float*)d_out);
}

// Round 17
// 543.595 us; speedup vs baseline: 2.1030x; 1.2259x over previous
//
#include <hip/hip_runtime.h>

#define NN 50000
#define NE 800000

typedef _Float16 f16;
typedef _Float16 f16x8 __attribute__((ext_vector_type(8)));
typedef float f32x4 __attribute__((ext_vector_type(4)));
typedef float f32x2 __attribute__((ext_vector_type(2)));

__device__ __forceinline__ f16x8 fzero8() {
  f16x8 v;
#pragma unroll
  for (int i = 0; i < 8; ++i) v[i] = (f16)0.f;
  return v;
}

__device__ __forceinline__ f32x4 mfma16(f16x8 a, f16x8 b, f32x4 c) {
  return __builtin_amdgcn_mfma_f32_16x16x32_f16(a, b, c, 0, 0, 0);
}

// decode 8 packed fp8(e4m3, native gfx950) -> f16x8 via HW cvt + scalar f32->f16
__device__ __forceinline__ f16x8 dec8(uint2 q) {
  f32x2 f0 = __builtin_amdgcn_cvt_pk_f32_fp8(q.x, false);
  f32x2 f1 = __builtin_amdgcn_cvt_pk_f32_fp8(q.x, true);
  f32x2 f2 = __builtin_amdgcn_cvt_pk_f32_fp8(q.y, false);
  f32x2 f3 = __builtin_amdgcn_cvt_pk_f32_fp8(q.y, true);
  f16x8 r;
  r[0] = (f16)f0[0]; r[1] = (f16)f0[1];
  r[2] = (f16)f1[0]; r[3] = (f16)f1[1];
  r[4] = (f16)f2[0]; r[5] = (f16)f2[1];
  r[6] = (f16)f3[0]; r[7] = (f16)f3[1];
  return r;
}

// encode f16x8 -> 8 packed fp8(e4m3)
__device__ __forceinline__ uint2 enc8(f16x8 v) {
  unsigned lo = 0, hi = 0;
  lo = __builtin_amdgcn_cvt_pk_fp8_f32((float)v[0], (float)v[1], lo, false);
  lo = __builtin_amdgcn_cvt_pk_fp8_f32((float)v[2], (float)v[3], lo, true);
  hi = __builtin_amdgcn_cvt_pk_fp8_f32((float)v[4], (float)v[5], hi, false);
  hi = __builtin_amdgcn_cvt_pk_fp8_f32((float)v[6], (float)v[7], hi, true);
  uint2 q; q.x = lo; q.y = hi;
  return q;
}

// ---------------- prep kernels ----------------

__global__ void count_kernel(const int* __restrict__ dst, int* __restrict__ cnt) {
  int e = blockIdx.x * 256 + threadIdx.x;
  if (e < NE) atomicAdd(&cnt[dst[e]], 1);
}

// ---- 3-phase hierarchical exclusive scan over cnt -> off/cur, plus inv ----
__global__ void blocksum_kernel(const int* __restrict__ cnt, int* __restrict__ bsum) {
  __shared__ int sdata[256];
  const int t = threadIdx.x;
  const int i = blockIdx.x * 256 + t;
  sdata[t] = (i < NN) ? cnt[i] : 0;
  __syncthreads();
#pragma unroll
  for (int d = 128; d > 0; d >>= 1) {
    if (t < d) sdata[t] += sdata[t + d];
    __syncthreads();
  }
  if (t == 0) bsum[blockIdx.x] = sdata[0];
}

__global__ void scan_bsum_kernel(const int* __restrict__ bsum, int* __restrict__ boff,
                                 int nblk) {
  __shared__ int sdata[256];
  const int t = threadIdx.x;
  sdata[t] = (t < nblk) ? bsum[t] : 0;
  __syncthreads();
  for (int d = 1; d < 256; d <<= 1) {
    int v = (t >= d) ? sdata[t - d] : 0;
    __syncthreads();
    sdata[t] += v;
    __syncthreads();
  }
  if (t < nblk) boff[t] = (t > 0) ? sdata[t - 1] : 0;
}

__global__ void write_off_kernel(const int* __restrict__ cnt, const int* __restrict__ boff,
                                 int* __restrict__ off, int* __restrict__ cur,
                                 float* __restrict__ inv) {
  __shared__ int sdata[256];
  const int t = threadIdx.x;
  const int i = blockIdx.x * 256 + t;
  const int v = (i < NN) ? cnt[i] : 0;
  sdata[t] = v;
  __syncthreads();
  for (int d = 1; d < 256; d <<= 1) {
    int w = (t >= d) ? sdata[t - d] : 0;
    __syncthreads();
    sdata[t] += w;
    __syncthreads();
  }
  if (i < NN) {
    const int excl = boff[blockIdx.x] + sdata[t] - v;
    off[i] = excl;
    cur[i] = excl;
    inv[i] = 1.0f / fmaxf((float)v, 1.0f);
    if (i == NN - 1) off[NN] = excl + v;
  }
}

// scatter edges into dst-sorted order; also build packed encoder rows
__global__ void scatter_pack(const float* __restrict__ x, const float* __restrict__ ea,
                             const int* __restrict__ src, const int* __restrict__ dst,
                             int* __restrict__ cur, int* __restrict__ psrc,
                             int* __restrict__ pdst, f16* __restrict__ A) {
  int e = blockIdx.x * 256 + threadIdx.x;
  if (e >= NE) return;
  int s = src[e], d = dst[e];
  int pos = atomicAdd(&cur[d], 1);
  psrc[pos] = s;
  pdst[pos] = d;
  f16 row[16];
#pragma unroll
  for (int i = 0; i < 5; ++i) { row[i] = (f16)x[s * 5 + i]; row[5 + i] = (f16)x[d * 5 + i]; }
#pragma unroll
  for (int i = 0; i < 4; ++i) row[10 + i] = (f16)ea[e * 4 + i];
  row[14] = (f16)0.f; row[15] = (f16)0.f;
  *(f16x8*)(A + (size_t)pos * 16) = *(f16x8*)row;
  *(f16x8*)(A + (size_t)pos * 16 + 8) = *(f16x8*)(row + 8);
}

// f16 xh -> fp8 gather mirror xq (3.2 MB, fits a 4MB XCD L2)
__global__ void xq_kernel(const f16* __restrict__ xh, unsigned char* __restrict__ xq) {
  int i = blockIdx.x * 256 + threadIdx.x;  // over NN*8 rows of 8 elems
  if (i >= NN * 8) return;
  f16x8 v = *(const f16x8*)(xh + (size_t)i * 8);
  uint2 q = enc8(v);
  *(uint2*)(xq + (size_t)i * 8) = q;
}

// all 13 weight transposes in one launch; block b handles matrix b
struct PrepPtrs { const float* W[13]; };
__global__ void prep_all(PrepPtrs P, f16* __restrict__ out) {
  const int Nw[13]   = {64,64,64,64,64,64,64,64,64,64,64,64,7};
  const int Kd[13]   = {32,64,96,96,64,192,64,128,64,192,64,128,64};
  const int ks[13]   = {0,0,0,5,0,0,0,0,0,0,0,0,0};
  const int kd[13]   = {0,0,0,32,0,0,0,0,0,0,0,0,0};
  const int klen[13] = {14,64,5,64,64,192,64,128,64,192,64,128,64};
  const int nc[13]   = {64,64,64,64,64,64,64,64,64,64,64,64,7};
  const int ofs[13]  = {0,2048,6144,6144,12288,16384,28672,32768,40960,45056,57344,61440,69632};
  const int m = blockIdx.x;
  const float* W = P.W[m];
  const int tot = klen[m] * nc[m];
  for (int idx = threadIdx.x; idx < tot; idx += 256) {
    int kk = idx / nc[m], n = idx % nc[m];
    out[ofs[m] + n * Kd[m] + kd[m] + kk] = (f16)W[(ks[m] + kk) * Nw[m] + n];
  }
}

// ---------------- edge MLP (R13 + fp8 src-gather + fp8 el stream) ----------------
// STAGE: 0=encoder (A from packed Aenc, write el fp8, agg += el)
//        1=processor (A=[fp8 xq[src]|xh[dst]|fp8 el], el += ed in place, agg += ed)
//        2=decoder   (A same as proc, NO el write, agg += ed)
template <int STAGE, int KT1>
__global__ __launch_bounds__(256, 3)
void edge_mlp_kernel(const f16* __restrict__ Aenc,
                     const f16* __restrict__ xh,
                     const unsigned char* __restrict__ xq,
                     const unsigned char* elr, unsigned char* elw,
                     const int* __restrict__ psrc,
                     const int* __restrict__ pdst,
                     const f16* __restrict__ B1,
                     const f16* __restrict__ B2,
                     const float* __restrict__ b1,
                     const float* __restrict__ b2,
                     float* __restrict__ agg) {
  constexpr int K1 = KT1 * 32;
  constexpr int NF1 = KT1 * 4;              // L1 fragment count
  constexpr int NA = (STAGE == 0) ? 1 : 2;  // f16 A fragments (dst only)
  __shared__ __align__(16) f16 h1s[4][16][72];    // 9216 B
  __shared__ __align__(16) f16 B1s[NF1 * 64 * 8]; // KT1=6: 24576 B
  __shared__ __align__(16) f16 B2s[8 * 64 * 8];   // 8192 B  (total 41984 -> 3 blk/CU)

  const int wave = threadIdx.x >> 6;
  const int lane = threadIdx.x & 63;
  const int l15 = lane & 15, lg = lane >> 4;
  const int NG = NE / 16;

  // XCD-partitioned mapping: 8 partitions of NG/8 contiguous groups
  const int xcd = blockIdx.x & 7;
  const int wlocal = (blockIdx.x >> 3) * 4 + wave;
  const int WPP = (gridDim.x >> 3) * 4;
  const int NGP = NG >> 3;
  const int gBase = xcd * NGP;
  const int gEnd = gBase + NGP;

  // ---- stage weight fragments into LDS (fragment-major, conflict-free reads) ----
  for (int f = wave; f < NF1; f += 4) {
    const int kk = f >> 2, nt = f & 3;
    *(f16x8*)&B1s[(f * 64 + lane) * 8] =
        *(const f16x8*)(B1 + (nt * 16 + l15) * K1 + kk * 32 + lg * 8);
  }
  for (int f = wave; f < 8; f += 4) {
    const int kk = f >> 2, nt = f & 3;
    *(f16x8*)&B2s[(f * 64 + lane) * 8] =
        *(const f16x8*)(B2 + (nt * 16 + l15) * 64 + kk * 32 + lg * 8);
  }
  float bias1[4], bias2[4];
#pragma unroll
  for (int nt = 0; nt < 4; ++nt) { bias1[nt] = b1[nt * 16 + l15]; bias2[nt] = b2[nt * 16 + l15]; }
  __syncthreads();

  // ---- A loaders: src + el from fp8 (uint2 x2 each), dst from f16 ----
  auto loadA = [&](int g, int s, int d, f16x8* a,
                   uint2& qs0, uint2& qs1, uint2& qe0, uint2& qe1) {
    const int erA = g * 16 + l15;
    if (STAGE == 0) {
      a[0] = fzero8();
      if (lg < 2) a[0] = *(const f16x8*)(Aenc + (size_t)erA * 16 + lg * 8);
    } else {
      qs0 = *(const uint2*)(xq + (size_t)s * 64 + lg * 8);
      qs1 = *(const uint2*)(xq + (size_t)s * 64 + 32 + lg * 8);
      a[0] = *(const f16x8*)(xh + (size_t)d * 64 + lg * 8);
      a[1] = *(const f16x8*)(xh + (size_t)d * 64 + 32 + lg * 8);
      qe0 = *(const uint2*)(elr + (size_t)erA * 64 + lg * 8);
      qe1 = *(const uint2*)(elr + (size_t)erA * 64 + 32 + lg * 8);
    }
  };

  // ---- software pipeline: idx 2-deep, A-frags 1-deep (R7-proven) ----
  const int g1 = gBase + wlocal;
  int sA = 0, dA = 0, sB = 0, dB = 0;
  dA = pdst[g1 * 16 + l15];
  if (STAGE != 0) sA = psrc[g1 * 16 + l15];
  f16x8 aCur[NA], aNxt[NA];
  uint2 qsC0, qsC1, qeC0, qeC1;
  uint2 qsN0, qsN1, qeN0, qeN1;
  loadA(g1, sA, dA, aCur, qsC0, qsC1, qeC0, qeC1);
  {
    const int g2 = g1 + WPP;
    if (g2 < gEnd) {
      dB = pdst[g2 * 16 + l15];
      if (STAGE != 0) sB = psrc[g2 * 16 + l15];
    }
  }

  for (int g = g1; g < gEnd; g += WPP) {
    const int gN = g + WPP;
    if (gN < gEnd) loadA(gN, sB, dB, aNxt, qsN0, qsN1, qeN0, qeN1);
    int sC = 0, dC = 0;
    const int g3 = g + 2 * WPP;
    if (g3 < gEnd) {
      dC = pdst[g3 * 16 + l15];
      if (STAGE != 0) sC = psrc[g3 * 16 + l15];
    }

    // decode el once per group (used by MFMA + residual epilogue)
    f16x8 eC0 = fzero8(), eC1 = fzero8();
    if (STAGE != 0) { eC0 = dec8(qeC0); eC1 = dec8(qeC1); }

    // ---- layer 1: MFMA with LDS B-frags ----
    f32x4 acc[4];
#pragma unroll
    for (int nt = 0; nt < 4; ++nt) { acc[nt][0] = 0.f; acc[nt][1] = 0.f; acc[nt][2] = 0.f; acc[nt][3] = 0.f; }
#pragma unroll
    for (int kk = 0; kk < KT1; ++kk) {
      f16x8 a;
      if (STAGE == 0) {
        a = aCur[0];
      } else {
        if (kk == 0)      a = dec8(qsC0);
        else if (kk == 1) a = dec8(qsC1);
        else if (kk < 4)  a = aCur[kk - 2];
        else              a = (kk == 4) ? eC0 : eC1;
      }
#pragma unroll
      for (int nt = 0; nt < 4; ++nt) {
        const f16x8 b = *(const f16x8*)&B1s[((kk * 4 + nt) * 64 + lane) * 8];
        acc[nt] = mfma16(a, b, acc[nt]);
      }
    }
    // bias + relu, stage h1 to LDS (C-layout -> A-layout); per-wave slice
#pragma unroll
    for (int nt = 0; nt < 4; ++nt)
#pragma unroll
      for (int r = 0; r < 4; ++r) {
        float h = fmaxf(acc[nt][r] + bias1[nt], 0.f);
        h1s[wave][lg * 4 + r][nt * 16 + l15] = (f16)h;
      }

    // ---- layer 2 ----
    f32x4 out[4];
#pragma unroll
    for (int nt = 0; nt < 4; ++nt) { out[nt][0] = 0.f; out[nt][1] = 0.f; out[nt][2] = 0.f; out[nt][3] = 0.f; }
#pragma unroll
    for (int kk = 0; kk < 2; ++kk) {
      const f16x8 hf = *(const f16x8*)&h1s[wave][l15][kk * 32 + lg * 8];
#pragma unroll
      for (int nt = 0; nt < 4; ++nt) {
        const f16x8 b = *(const f16x8*)&B2s[((kk * 4 + nt) * 64 + lane) * 8];
        out[nt] = mfma16(hf, b, out[nt]);
      }
    }

    // stage ed (bias added) back to LDS rows
#pragma unroll
    for (int nt = 0; nt < 4; ++nt)
#pragma unroll
      for (int r = 0; r < 4; ++r)
        h1s[wave][lg * 4 + r][nt * 16 + l15] = (f16)(out[nt][r] + bias2[nt]);

    // global el write (fp8; encoder: fresh; proc: in-place residual; decoder: none)
    const int erA = g * 16 + l15;
    if (STAGE != 2) {
      f16x8 v0 = *(const f16x8*)&h1s[wave][l15][lg * 8];
      f16x8 v1 = *(const f16x8*)&h1s[wave][l15][32 + lg * 8];
      unsigned char* p0 = elw + (size_t)erA * 64 + lg * 8;
      if (STAGE == 1) {
        f16x8 n0, n1;
#pragma unroll
        for (int j = 0; j < 8; ++j) {
          n0[j] = (f16)((float)eC0[j] + (float)v0[j]);
          n1[j] = (f16)((float)eC1[j] + (float)v1[j]);
        }
        *(uint2*)p0 = enc8(n0);
        *(uint2*)(p0 + 32) = enc8(n1);
      } else {
        *(uint2*)p0 = enc8(v0);
        *(uint2*)(p0 + 32) = enc8(v1);
      }
    }

    // fused segmented reduction: lane = column, walk 16 sorted rows,
    // one coalesced 64-lane atomicAdd per dst segment (dst wave-uniform).
    {
      float racc = 0.f;
      int dprev = __shfl(dA, 0);
#pragma unroll
      for (int row = 0; row < 16; ++row) {
        const int dn = __shfl(dA, row);
        const float v = (float)h1s[wave][row][lane];
        if (dn != dprev) {
          atomicAdd(agg + (size_t)dprev * 64 + lane, racc);
          racc = 0.f;
          dprev = dn;
        }
        racc += v;
      }
      atomicAdd(agg + (size_t)dprev * 64 + lane, racc);
    }

    // rotate pipeline
#pragma unroll
    for (int i = 0; i < NA; ++i) aCur[i] = aNxt[i];
    qsC0 = qsN0; qsC1 = qsN1; qeC0 = qeN0; qeC1 = qeN1;
    sA = sB; dA = dB; sB = sC; dB = dC;
  }
}

// ---------------- node MLP (LDS-staged weights, fused mean-finish) ----------------
// STAGE: 0=encoder (A=[x_raw(5,pad32)|agg*inv], out: xl=v, xh=f16(v))
//        1=processor (A=[xh|agg*inv], xl += v, xh mirror)
//        2=decoder   (A=[xh|agg*inv], write d_out[N][7])
template <int STAGE, int KT1, int NT2, int OUTW>
__global__ __launch_bounds__(256, 4)
void node_mlp_kernel(const float* __restrict__ xraw,
                     const f16* xh,
                     const float* __restrict__ agg,
                     const float* __restrict__ inv,
                     const f16* __restrict__ B1,
                     const f16* __restrict__ B2,
                     const float* __restrict__ b1,
                     const float* __restrict__ b2,
                     float* __restrict__ xl,
                     f16* xho,
                     float* __restrict__ outp) {
  constexpr int K1 = KT1 * 32;
  constexpr int NF1 = KT1 * 4;
  constexpr int NF2 = 2 * NT2;
  __shared__ __align__(16) f16 h1s[4][16][72];
  __shared__ __align__(16) f16 B1s[NF1 * 64 * 8];
  __shared__ __align__(16) f16 B2s[NF2 * 64 * 8];
  const int wave = threadIdx.x >> 6;
  const int lane = threadIdx.x & 63;
  const int l15 = lane & 15, lg = lane >> 4;
  const int nwaves = gridDim.x * 4;
  const int wid = blockIdx.x * 4 + wave;
  const int NG = NN / 16;

  for (int f = wave; f < NF1; f += 4) {
    const int kk = f >> 2, nt = f & 3;
    *(f16x8*)&B1s[(f * 64 + lane) * 8] =
        *(const f16x8*)(B1 + (nt * 16 + l15) * K1 + kk * 32 + lg * 8);
  }
  for (int f = wave; f < NF2; f += 4) {
    const int kk = f / NT2, nt = f % NT2;
    *(f16x8*)&B2s[(f * 64 + lane) * 8] =
        *(const f16x8*)(B2 + (nt * 16 + l15) * 64 + kk * 32 + lg * 8);
  }
  float bias1[4], bias2[NT2];
#pragma unroll
  for (int nt = 0; nt < 4; ++nt) bias1[nt] = b1[nt * 16 + l15];
#pragma unroll
  for (int nt = 0; nt < NT2; ++nt) bias2[nt] = (nt * 16 + l15 < OUTW) ? b2[nt * 16 + l15] : 0.f;
  __syncthreads();

  for (int g = wid; g < NG; g += nwaves) {
    const int n0 = g * 16;
    const int rA = n0 + l15;
    const float iv = inv[rA];

    f32x4 acc[4];
#pragma unroll
    for (int nt = 0; nt < 4; ++nt) { acc[nt][0] = 0.f; acc[nt][1] = 0.f; acc[nt][2] = 0.f; acc[nt][3] = 0.f; }

#pragma unroll
    for (int kk = 0; kk < KT1; ++kk) {
      f16x8 a;
      if (STAGE == 0 && kk == 0) {
        a = fzero8();
        if (lg == 0) {
#pragma unroll
          for (int j = 0; j < 5; ++j) a[j] = (f16)xraw[(size_t)rA * 5 + j];
        }
      } else if (STAGE != 0 && kk < 2) {
        a = *(const f16x8*)(xh + (size_t)rA * 64 + kk * 32 + lg * 8);
      } else {
        const int ko = (STAGE == 0) ? (kk - 1) : (kk - 2);
        const float* ap = agg + (size_t)rA * 64 + ko * 32 + lg * 8;
        f32x4 a0 = *(const f32x4*)ap;
        f32x4 a1 = *(const f32x4*)(ap + 4);
#pragma unroll
        for (int j = 0; j < 4; ++j) { a[j] = (f16)(a0[j] * iv); a[4 + j] = (f16)(a1[j] * iv); }
      }
#pragma unroll
      for (int nt = 0; nt < 4; ++nt) {
        const f16x8 b = *(const f16x8*)&B1s[((kk * 4 + nt) * 64 + lane) * 8];
        acc[nt] = mfma16(a, b, acc[nt]);
      }
    }
#pragma unroll
    for (int nt = 0; nt < 4; ++nt)
#pragma unroll
      for (int r = 0; r < 4; ++r) {
        float h = fmaxf(acc[nt][r] + bias1[nt], 0.f);
        h1s[wave][lg * 4 + r][nt * 16 + l15] = (f16)h;
      }

    f32x4 out[NT2];
#pragma unroll
    for (int nt = 0; nt < NT2; ++nt) { out[nt][0] = 0.f; out[nt][1] = 0.f; out[nt][2] = 0.f; out[nt][3] = 0.f; }
#pragma unroll
    for (int kk = 0; kk < 2; ++kk) {
      const f16x8 hf = *(const f16x8*)&h1s[wave][l15][kk * 32 + lg * 8];
#pragma unroll
      for (int nt = 0; nt < NT2; ++nt) {
        const f16x8 b = *(const f16x8*)&B2s[((kk * NT2 + nt) * 64 + lane) * 8];
        out[nt] = mfma16(hf, b, out[nt]);
      }
    }
#pragma unroll
    for (int r = 0; r < 4; ++r) {
      const int row = n0 + lg * 4 + r;
#pragma unroll
      for (int nt = 0; nt < NT2; ++nt) {
        const int col = nt * 16 + l15;
        float v = out[nt][r] + bias2[nt];
        if (STAGE == 0) {
          xl[(size_t)row * 64 + col] = v;
          xho[(size_t)row * 64 + col] = (f16)v;
        } else if (STAGE == 1) {
          float nv = xl[(size_t)row * 64 + col] + v;
          xl[(size_t)row * 64 + col] = nv;
          xho[(size_t)row * 64 + col] = (f16)nv;
        } else {
          if (col < OUTW) outp[(size_t)row * OUTW + col] = v;
        }
      }
    }
  }
}

// ---------------- launch ----------------

extern "C" void kernel_launch(void* const* d_in, const int* in_sizes, int n_in,
                              void* d_out, int out_size, void* d_ws, size_t ws_size,
                              hipStream_t stream) {
  const float* x  = (const float*)d_in[0];
  const int* ei   = (const int*)d_in[1];
  const float* ea = (const float*)d_in[2];
  const float* enc_e_b1 = (const float*)d_in[4];
  const float* enc_e_b2 = (const float*)d_in[6];
  const float* enc_n_b1 = (const float*)d_in[8];
  const float* enc_n_b2 = (const float*)d_in[10];
  const float* proc_e_b1 = (const float*)d_in[12];
  const float* proc_e_b2 = (const float*)d_in[14];
  const float* proc_n_b1 = (const float*)d_in[16];
  const float* proc_n_b2 = (const float*)d_in[18];
  const float* dec_e_b1 = (const float*)d_in[20];
  const float* dec_e_b2 = (const float*)d_in[22];
  const float* dec_n_b1 = (const float*)d_in[24];
  const float* dec_n_b2 = (const float*)d_in[26];

  const int* src = ei;
  const int* dst = ei + NE;

  // workspace layout (~120 MB total; R2 proved >= 263 MB available)
  char* p = (char*)d_ws;
  unsigned char* el = (unsigned char*)p; p += (size_t)NE * 64;  // 51.2 MB fp8 edge latents
  f16* Aenc  = (f16*)p;   p += (size_t)NE * 16 * 2;   // 25.6 MB
  float* xl  = (float*)p; p += (size_t)NN * 64 * 4;   // 12.8 MB
  f16* xh    = (f16*)p;   p += (size_t)NN * 64 * 2;   // 6.4 MB
  unsigned char* xq = (unsigned char*)p; p += (size_t)NN * 64;  // 3.2 MB fp8 mirror
  float* agg = (float*)p; p += (size_t)NN * 64 * 4;   // 12.8 MB f32 atomic accumulator
  int* cnt   = (int*)p;   p += (size_t)NN * 4;
  int* off   = (int*)p;   p += (size_t)(NN + 1) * 4;
  int* cur   = (int*)p;   p += (size_t)NN * 4;
  float* inv = (float*)p; p += (size_t)NN * 4;
  int* bsum  = (int*)p;   p += 256 * 4;
  int* boff  = (int*)p;   p += 256 * 4;
  int* psrc  = (int*)p;   p += (size_t)NE * 4;
  int* pdst  = (int*)p;   p += (size_t)NE * 4;
  f16* wb    = (f16*)p;   p += 70656 * 2;
  f16* W1T_ence = wb + 0;
  f16* W2T_ence = wb + 2048;
  f16* W1T_encn = wb + 6144;
  f16* W2T_encn = wb + 12288;
  f16* W1T_proce = wb + 16384;
  f16* W2T_proce = wb + 28672;
  f16* W1T_procn = wb + 32768;
  f16* W2T_procn = wb + 40960;
  f16* W1T_dece = wb + 45056;
  f16* W2T_dece = wb + 57344;
  f16* W1T_decn = wb + 61440;
  f16* W2T_decn = wb + 69632;

  hipMemsetAsync(cnt, 0, (size_t)NN * 4, stream);
  hipMemsetAsync(wb, 0, 70656 * 2, stream);

  const int SCAN_NBLK = (NN + 255) / 256;  // 196
  count_kernel<<<(NE + 255) / 256, 256, 0, stream>>>(dst, cnt);
  blocksum_kernel<<<SCAN_NBLK, 256, 0, stream>>>(cnt, bsum);
  scan_bsum_kernel<<<1, 256, 0, stream>>>(bsum, boff, SCAN_NBLK);
  write_off_kernel<<<SCAN_NBLK, 256, 0, stream>>>(cnt, boff, off, cur, inv);
  scatter_pack<<<(NE + 255) / 256, 256, 0, stream>>>(x, ea, src, dst, cur, psrc, pdst, Aenc);

  PrepPtrs P;
  P.W[0]  = (const float*)d_in[3];   // enc_e_w1
  P.W[1]  = (const float*)d_in[5];   // enc_e_w2
  P.W[2]  = (const float*)d_in[7];   // enc_n_w1 (raw part)
  P.W[3]  = (const float*)d_in[7];   // enc_n_w1 (agg part)
  P.W[4]  = (const float*)d_in[9];   // enc_n_w2
  P.W[5]  = (const float*)d_in[11];  // proc_e_w1
  P.W[6]  = (const float*)d_in[13];  // proc_e_w2
  P.W[7]  = (const float*)d_in[15];  // proc_n_w1
  P.W[8]  = (const float*)d_in[17];  // proc_n_w2
  P.W[9]  = (const float*)d_in[19];  // dec_e_w1
  P.W[10] = (const float*)d_in[21];  // dec_e_w2
  P.W[11] = (const float*)d_in[23];  // dec_n_w1
  P.W[12] = (const float*)d_in[25];  // dec_n_w2
  prep_all<<<13, 256, 0, stream>>>(P, wb);

  // 768 blocks = 96 per XCD = exactly 3 resident blocks/CU; XCD-partitioned mapping
  const int EDGE_BLK = 768;
  const int XQ_BLK = (NN * 8 + 255) / 256;
  const size_t AGG_BYTES = (size_t)NN * 64 * 4;

  // ---- encoder ----
  hipMemsetAsync(agg, 0, AGG_BYTES, stream);
  edge_mlp_kernel<0, 1><<<EDGE_BLK, 256, 0, stream>>>(Aenc, xh, xq, el, el, psrc, pdst,
                                                      W1T_ence, W2T_ence, enc_e_b1, enc_e_b2, agg);
  node_mlp_kernel<0, 3, 4, 64><<<256, 256, 0, stream>>>(x, xh, agg, inv, W1T_encn, W2T_encn,
                                                        enc_n_b1, enc_n_b2, xl, xh, (float*)d_out);
  xq_kernel<<<XQ_BLK, 256, 0, stream>>>(xh, xq);
  // ---- 2 processor rounds (shared weights, residuals) ----
  for (int r = 0; r < 2; ++r) {
    hipMemsetAsync(agg, 0, AGG_BYTES, stream);
    edge_mlp_kernel<1, 6><<<EDGE_BLK, 256, 0, stream>>>(Aenc, xh, xq, el, el, psrc, pdst,
                                                        W1T_proce, W2T_proce, proc_e_b1, proc_e_b2, agg);
    node_mlp_kernel<1, 4, 4, 64><<<256, 256, 0, stream>>>(x, xh, agg, inv, W1T_procn, W2T_procn,
                                                          proc_n_b1, proc_n_b2, xl, xh, (float*)d_out);
    xq_kernel<<<XQ_BLK, 256, 0, stream>>>(xh, xq);
  }
  // ---- decoder (no el write; agg of ed only) ----
  hipMemsetAsync(agg, 0, AGG_BYTES, stream);
  edge_mlp_kernel<2, 6><<<EDGE_BLK, 256, 0, stream>>>(Aenc, xh, xq, el, el, psrc, pdst,
                                                      W1T_dece, W2T_dece, dec_e_b1, dec_e_b2, agg);
  node_mlp_kernel<2, 4, 1, 7><<<256, 256, 0, stream>>>(x, xh, agg, inv, W1T_decn, W2T_decn,
                                                       dec_n_b1, dec_n_b2, xl, xh, (float*)d_out);
}